// Round 1
// baseline (992.024 us; speedup 1.0000x reference)
//
#include <hip/hip_runtime.h>
#include <math.h>

#define D_DIM 128
#define N_DST 50000
#define N_SRC 50000
#define NE    800000
#define NEG_SLOPE 0.2f

// ---------------------------------------------------------------------------
// wal_r = Wg_r @ al_r,  war_r = Wg_r @ ar_r   (collapses hd GEMM to a matvec)
// wv layout: [0..2]=wal0..2, [3..5]=war0..2, each 128 floats
__global__ void vec_kernel(const float* __restrict__ Wg0, const float* __restrict__ Wg1,
                           const float* __restrict__ Wg2,
                           const float* __restrict__ al0, const float* __restrict__ al1,
                           const float* __restrict__ al2,
                           const float* __restrict__ ar0, const float* __restrict__ ar1,
                           const float* __restrict__ ar2,
                           float* __restrict__ wv) {
    int r = blockIdx.x;
    const float* W  = r == 0 ? Wg0 : (r == 1 ? Wg1 : Wg2);
    const float* al = r == 0 ? al0 : (r == 1 ? al1 : al2);
    const float* ar = r == 0 ? ar0 : (r == 1 ? ar1 : ar2);
    int i = threadIdx.x;
    float sal = 0.f, sar = 0.f;
    for (int j = 0; j < D_DIM; j++) {
        float w = W[i * D_DIM + j];
        sal = fmaf(w, al[j], sal);
        sar = fmaf(w, ar[j], sar);
    }
    wv[r * D_DIM + i]       = sal;
    wv[(3 + r) * D_DIM + i] = sar;
}

// ---------------------------------------------------------------------------
// elv[j][n] = dot(M_j[n,:], wv[j])  for 6 jobs (el0..2 from src feats, er0..2 from dst)
// wave-per-row, 4 rows/block
__global__ void matvec_kernel(const float* __restrict__ src0, const float* __restrict__ src1,
                              const float* __restrict__ src2, const float* __restrict__ dstf,
                              const float* __restrict__ wv, float* __restrict__ elv) {
    int job  = blockIdx.x / 12500;
    int blk  = blockIdx.x % 12500;
    int wave = threadIdx.x >> 6;
    int lane = threadIdx.x & 63;
    int row  = blk * 4 + wave;
    const float* M = job == 0 ? src0 : (job == 1 ? src1 : (job == 2 ? src2 : dstf));
    const float* v = wv + job * D_DIM;
    const float* mr = M + (size_t)row * D_DIM;
    float p = fmaf(mr[lane], v[lane], mr[lane + 64] * v[lane + 64]);
    #pragma unroll
    for (int off = 32; off > 0; off >>= 1) p += __shfl_down(p, off);
    if (lane == 0) elv[job * N_DST + row] = p;
}

// ---------------------------------------------------------------------------
// fp32 GEMM: C[nrows,128] = A[nrows,128] @ W[128,128]
// 32-row x 128-col block tile, 4x4 outputs/thread, W staged in K=32 chunks
__global__ __launch_bounds__(256) void gemm_kernel(const float* __restrict__ A,
                                                   const float* __restrict__ W,
                                                   float* __restrict__ C, int nrows) {
    __shared__ __align__(16) float As[32][128];
    __shared__ __align__(16) float Ws[32][128];
    int tid  = threadIdx.x;
    int row0 = blockIdx.x * 32;
    int colg = tid & 31, rowg = tid >> 5;
    int col4 = colg * 4;

    #pragma unroll
    for (int j = 0; j < 4; j++) {          // stage A tile (full K)
        int f4 = tid + j * 256;
        int m = f4 >> 5, k4 = (f4 & 31) * 4;
        int gr = row0 + m; if (gr > nrows - 1) gr = nrows - 1;
        *(float4*)&As[m][k4] = *(const float4*)&A[(size_t)gr * 128 + k4];
    }

    float acc[4][4] = {};
    for (int kb = 0; kb < 4; kb++) {
        #pragma unroll
        for (int j = 0; j < 4; j++) {      // stage W chunk (32 k-rows)
            int f4 = tid + j * 256;
            int kk = f4 >> 5, n4 = (f4 & 31) * 4;
            *(float4*)&Ws[kk][n4] = *(const float4*)&W[(size_t)(kb * 32 + kk) * 128 + n4];
        }
        __syncthreads();
        #pragma unroll
        for (int kk = 0; kk < 32; kk += 4) {
            float a_[4][4], w_[4][4];
            #pragma unroll
            for (int r_ = 0; r_ < 4; r_++) {
                float4 t = *(const float4*)&As[rowg * 4 + r_][kb * 32 + kk];
                a_[r_][0] = t.x; a_[r_][1] = t.y; a_[r_][2] = t.z; a_[r_][3] = t.w;
            }
            #pragma unroll
            for (int k_ = 0; k_ < 4; k_++) {
                float4 t = *(const float4*)&Ws[kk + k_][col4];
                w_[k_][0] = t.x; w_[k_][1] = t.y; w_[k_][2] = t.z; w_[k_][3] = t.w;
            }
            #pragma unroll
            for (int k_ = 0; k_ < 4; k_++)
                #pragma unroll
                for (int r_ = 0; r_ < 4; r_++)
                    #pragma unroll
                    for (int c_ = 0; c_ < 4; c_++)
                        acc[r_][c_] = fmaf(a_[r_][k_], w_[k_][c_], acc[r_][c_]);
        }
        __syncthreads();
    }
    #pragma unroll
    for (int r_ = 0; r_ < 4; r_++) {
        int gr = row0 + rowg * 4 + r_;
        if (gr < nrows) {
            float4 t = make_float4(acc[r_][0], acc[r_][1], acc[r_][2], acc[r_][3]);
            *(float4*)&C[(size_t)gr * 128 + col4] = t;
        }
    }
}

// ---------------------------------------------------------------------------
// CSR build
__global__ void hist_kernel(const int* __restrict__ d0, const int* __restrict__ d1,
                            const int* __restrict__ d2, int* __restrict__ counts) {
    int id = blockIdx.x * 256 + threadIdx.x;
    if (id >= 3 * NE) return;
    int r = id / NE, e = id - r * NE;
    const int* dd = r == 0 ? d0 : (r == 1 ? d1 : d2);
    atomicAdd(&counts[r * N_DST + dd[e]], 1);
}

__global__ void scan_kernel(const int* __restrict__ counts, int* __restrict__ offs,
                            int* __restrict__ cursor) {
    __shared__ int ssc[1024];
    int r = blockIdx.x, tid = threadIdx.x;
    const int* cnt = counts + r * N_DST;
    int* ofs = offs + r * (N_DST + 1);
    int* cur = cursor + r * N_DST;
    int running = 0;
    for (int base = 0; base < N_DST; base += 1024) {
        int i = base + tid;
        int c = (i < N_DST) ? cnt[i] : 0;
        ssc[tid] = c;
        __syncthreads();
        for (int off = 1; off < 1024; off <<= 1) {
            int v = (tid >= off) ? ssc[tid - off] : 0;
            __syncthreads();
            ssc[tid] += v;
            __syncthreads();
        }
        int excl  = ssc[tid] - c;
        int total = ssc[1023];
        if (i < N_DST) { int val = running + excl; ofs[i] = val; cur[i] = val; }
        running += total;
        __syncthreads();
    }
    if (tid == 0) ofs[N_DST] = running;
}

__global__ void scatter_kernel(const int* __restrict__ d0, const int* __restrict__ d1,
                               const int* __restrict__ d2,
                               const int* __restrict__ s0, const int* __restrict__ s1,
                               const int* __restrict__ s2,
                               int* __restrict__ cursor, int* __restrict__ perm) {
    int id = blockIdx.x * 256 + threadIdx.x;
    if (id >= 3 * NE) return;
    int r = id / NE, e = id - r * NE;
    const int* dd = r == 0 ? d0 : (r == 1 ? d1 : d2);
    const int* ss = r == 0 ? s0 : (r == 1 ? s1 : s2);
    int pos = atomicAdd(&cursor[r * N_DST + dd[e]], 1);
    perm[(size_t)r * NE + pos] = ss[e];   // store src index directly
}

// ---------------------------------------------------------------------------
// per-dst edge softmax + weighted feature aggregation (+ bias + elu)
__global__ __launch_bounds__(128) void aggregate_kernel(
        const float* __restrict__ hs, const float* __restrict__ el,
        const float* __restrict__ er, const int* __restrict__ perm,
        const int* __restrict__ offs, const float* __restrict__ bg,
        float* __restrict__ zm, int r) {
    __shared__ float wsh[128];
    __shared__ int   ssh[128];
    __shared__ float red[2];
    int b = blockIdx.x, tid = threadIdx.x;
    int o0 = offs[b], o1 = offs[b + 1], deg = o1 - o0;
    float erb = er[b];

    // pass 1: max
    float lmax = -INFINITY;
    for (int i = tid; i < deg; i += 128) {
        int s = perm[o0 + i];
        float x = el[s] + erb;
        x = x >= 0.f ? x : NEG_SLOPE * x;
        lmax = fmaxf(lmax, x);
    }
    #pragma unroll
    for (int off = 32; off > 0; off >>= 1) lmax = fmaxf(lmax, __shfl_down(lmax, off));
    if ((tid & 63) == 0) red[tid >> 6] = lmax;
    __syncthreads();
    float m = fmaxf(red[0], red[1]);
    __syncthreads();

    // pass 2: sum of exp
    float lsum = 0.f;
    for (int i = tid; i < deg; i += 128) {
        int s = perm[o0 + i];
        float x = el[s] + erb;
        x = x >= 0.f ? x : NEG_SLOPE * x;
        lsum += expf(x - m);
    }
    #pragma unroll
    for (int off = 32; off > 0; off >>= 1) lsum += __shfl_down(lsum, off);
    if ((tid & 63) == 0) red[tid >> 6] = lsum;
    __syncthreads();
    float zsum = red[0] + red[1];
    float invz = deg > 0 ? 1.f / zsum : 0.f;

    // pass 3: weighted feature accumulation (chunks of 128 edges via LDS broadcast)
    float acc = 0.f;
    for (int c0 = 0; c0 < deg; c0 += 128) {
        int n = min(128, deg - c0);
        __syncthreads();
        if (tid < n) {
            int s = perm[o0 + c0 + tid];
            float x = el[s] + erb;
            x = x >= 0.f ? x : NEG_SLOPE * x;
            wsh[tid] = expf(x - m) * invz;
            ssh[tid] = s;
        }
        __syncthreads();
        int j = 0;
        for (; j + 4 <= n; j += 4) {
            float w0 = wsh[j], w1 = wsh[j+1], w2 = wsh[j+2], w3 = wsh[j+3];
            int   s0 = ssh[j], s1 = ssh[j+1], s2 = ssh[j+2], s3 = ssh[j+3];
            float h0 = hs[(size_t)s0 * 128 + tid];
            float h1 = hs[(size_t)s1 * 128 + tid];
            float h2 = hs[(size_t)s2 * 128 + tid];
            float h3 = hs[(size_t)s3 * 128 + tid];
            acc = fmaf(w0, h0, acc); acc = fmaf(w1, h1, acc);
            acc = fmaf(w2, h2, acc); acc = fmaf(w3, h3, acc);
        }
        for (; j < n; j++) acc = fmaf(wsh[j], hs[(size_t)ssh[j] * 128 + tid], acc);
    }
    float z = acc + bg[tid];
    z = z > 0.f ? z : expm1f(z);
    zm[((size_t)b * 3 + r) * 128 + tid] = z;
}

// ---------------------------------------------------------------------------
// semantic attention: h[n,r] = tanh(zm[n,r,:]@W1 + b1) @ W2, atomically summed into w_sum[3]
__global__ __launch_bounds__(256) void semantic_kernel(const float* __restrict__ A,
                                                       const float* __restrict__ W1,
                                                       const float* __restrict__ b1,
                                                       const float* __restrict__ W2,
                                                       float* __restrict__ w_sum) {
    __shared__ __align__(16) float As[32][128];
    __shared__ __align__(16) float Ws[32][128];
    __shared__ float hsum[3];
    const int nrows = N_DST * 3;
    int tid  = threadIdx.x;
    if (tid < 3) hsum[tid] = 0.f;
    int row0 = blockIdx.x * 32;
    int colg = tid & 31, rowg = tid >> 5;
    int col4 = colg * 4;

    #pragma unroll
    for (int j = 0; j < 4; j++) {
        int f4 = tid + j * 256;
        int m = f4 >> 5, k4 = (f4 & 31) * 4;
        int gr = row0 + m; if (gr > nrows - 1) gr = nrows - 1;
        *(float4*)&As[m][k4] = *(const float4*)&A[(size_t)gr * 128 + k4];
    }

    float acc[4][4] = {};
    for (int kb = 0; kb < 4; kb++) {
        #pragma unroll
        for (int j = 0; j < 4; j++) {
            int f4 = tid + j * 256;
            int kk = f4 >> 5, n4 = (f4 & 31) * 4;
            *(float4*)&Ws[kk][n4] = *(const float4*)&W1[(size_t)(kb * 32 + kk) * 128 + n4];
        }
        __syncthreads();
        #pragma unroll
        for (int kk = 0; kk < 32; kk += 4) {
            float a_[4][4], w_[4][4];
            #pragma unroll
            for (int r_ = 0; r_ < 4; r_++) {
                float4 t = *(const float4*)&As[rowg * 4 + r_][kb * 32 + kk];
                a_[r_][0] = t.x; a_[r_][1] = t.y; a_[r_][2] = t.z; a_[r_][3] = t.w;
            }
            #pragma unroll
            for (int k_ = 0; k_ < 4; k_++) {
                float4 t = *(const float4*)&Ws[kk + k_][col4];
                w_[k_][0] = t.x; w_[k_][1] = t.y; w_[k_][2] = t.z; w_[k_][3] = t.w;
            }
            #pragma unroll
            for (int k_ = 0; k_ < 4; k_++)
                #pragma unroll
                for (int r_ = 0; r_ < 4; r_++)
                    #pragma unroll
                    for (int c_ = 0; c_ < 4; c_++)
                        acc[r_][c_] = fmaf(a_[r_][k_], w_[k_][c_], acc[r_][c_]);
        }
        __syncthreads();
    }

    // epilogue: tanh, dot with W2, reduce across the 32 column-threads per row
    float4 b1v = *(const float4*)&b1[col4];
    float4 w2v = *(const float4*)&W2[col4];
    float bb[4] = {b1v.x, b1v.y, b1v.z, b1v.w};
    float ww[4] = {w2v.x, w2v.y, w2v.z, w2v.w};
    float part[4];
    #pragma unroll
    for (int r_ = 0; r_ < 4; r_++) {
        float s = 0.f;
        #pragma unroll
        for (int c_ = 0; c_ < 4; c_++)
            s = fmaf(tanhf(acc[r_][c_] + bb[c_]), ww[c_], s);
        part[r_] = s;
    }
    #pragma unroll
    for (int m_ = 16; m_ > 0; m_ >>= 1)
        #pragma unroll
        for (int r_ = 0; r_ < 4; r_++) part[r_] += __shfl_xor(part[r_], m_);
    if (colg == 0) {
        #pragma unroll
        for (int r_ = 0; r_ < 4; r_++) {
            int gr = row0 + rowg * 4 + r_;
            if (gr < nrows) atomicAdd(&hsum[gr % 3], part[r_]);
        }
    }
    __syncthreads();
    if (tid < 3) atomicAdd(&w_sum[tid], hsum[tid]);
}

// ---------------------------------------------------------------------------
__global__ void finalize_kernel(const float* __restrict__ w_sum, float* __restrict__ aw,
                                float* __restrict__ out_att) {
    if (threadIdx.x == 0 && blockIdx.x == 0) {
        float w0 = w_sum[0] / (float)N_DST;
        float w1 = w_sum[1] / (float)N_DST;
        float w2 = w_sum[2] / (float)N_DST;
        float m = fmaxf(w0, fmaxf(w1, w2));
        float e0 = expf(w0 - m), e1 = expf(w1 - m), e2 = expf(w2 - m);
        float s = e0 + e1 + e2;
        aw[0] = e0 / s; aw[1] = e1 / s; aw[2] = e2 / s;
        out_att[0] = aw[0]; out_att[1] = aw[1]; out_att[2] = aw[2];
    }
}

__global__ void combine_kernel(const float* __restrict__ zm, const float* __restrict__ aw,
                               float* __restrict__ out) {
    int id4 = blockIdx.x * 256 + threadIdx.x;   // 1.6M float4s
    float a0 = aw[0], a1 = aw[1], a2 = aw[2];
    int n  = id4 >> 5;
    int d4 = (id4 & 31) * 4;
    const float4 z0 = *(const float4*)&zm[((size_t)n * 3 + 0) * 128 + d4];
    const float4 z1 = *(const float4*)&zm[((size_t)n * 3 + 1) * 128 + d4];
    const float4 z2 = *(const float4*)&zm[((size_t)n * 3 + 2) * 128 + d4];
    float4 o;
    o.x = a0 * z0.x + a1 * z1.x + a2 * z2.x;
    o.y = a0 * z0.y + a1 * z1.y + a2 * z2.y;
    o.z = a0 * z0.z + a1 * z1.z + a2 * z2.z;
    o.w = a0 * z0.w + a1 * z1.w + a2 * z2.w;
    *(float4*)&out[(size_t)n * 128 + d4] = o;
}

// ---------------------------------------------------------------------------
extern "C" void kernel_launch(void* const* d_in, const int* in_sizes, int n_in,
                              void* d_out, int out_size, void* d_ws, size_t ws_size,
                              hipStream_t stream) {
    const float* dstf   = (const float*)d_in[0];
    const float* src0   = (const float*)d_in[1];
    const float* src1   = (const float*)d_in[2];
    const float* src2   = (const float*)d_in[3];
    const float* sem_W1 = (const float*)d_in[4];
    const float* sem_b1 = (const float*)d_in[5];
    const float* sem_W2 = (const float*)d_in[6];
    const float* Wg[3]  = {(const float*)d_in[7],  (const float*)d_in[13], (const float*)d_in[19]};
    const float* al[3]  = {(const float*)d_in[8],  (const float*)d_in[14], (const float*)d_in[20]};
    const float* ar[3]  = {(const float*)d_in[9],  (const float*)d_in[15], (const float*)d_in[21]};
    const float* bg[3]  = {(const float*)d_in[10], (const float*)d_in[16], (const float*)d_in[22]};
    const int*  sidx[3] = {(const int*)d_in[11], (const int*)d_in[17], (const int*)d_in[23]};
    const int*  didx[3] = {(const int*)d_in[12], (const int*)d_in[18], (const int*)d_in[24]};
    float* out = (float*)d_out;

    char* p = (char*)d_ws;
    auto alloc = [&](size_t bytes) -> char* {
        char* q = p; p += (bytes + 255) & ~(size_t)255; return q;
    };
    float* zm     = (float*)alloc((size_t)N_DST * 3 * 128 * 4);   // 76.8 MB
    float* hs     = (float*)alloc((size_t)N_SRC * 128 * 4);       // 25.6 MB (reused per relation)
    float* elv    = (float*)alloc((size_t)6 * N_DST * 4);         // el0..2, er0..2
    float* wv     = (float*)alloc((size_t)6 * 128 * 4);           // wal0..2, war0..2
    float* wsum   = (float*)alloc((size_t)16 * 4);                // w_sum[3] + aw[3]
    float* aw     = wsum + 8;
    int*   counts = (int*)alloc((size_t)3 * N_DST * 4);
    int*   offs   = (int*)alloc((size_t)3 * (N_DST + 1) * 4);
    int*   cursor = (int*)alloc((size_t)3 * N_DST * 4);
    int*   perm   = (int*)alloc((size_t)3 * NE * 4);

    hipMemsetAsync(counts, 0, (size_t)3 * N_DST * 4, stream);
    hipMemsetAsync(wsum, 0, (size_t)16 * 4, stream);

    vec_kernel<<<3, 128, 0, stream>>>(Wg[0], Wg[1], Wg[2], al[0], al[1], al[2],
                                      ar[0], ar[1], ar[2], wv);
    matvec_kernel<<<75000, 256, 0, stream>>>(src0, src1, src2, dstf, wv, elv);
    hist_kernel<<<(3 * NE + 255) / 256, 256, 0, stream>>>(didx[0], didx[1], didx[2], counts);
    scan_kernel<<<3, 1024, 0, stream>>>(counts, offs, cursor);
    scatter_kernel<<<(3 * NE + 255) / 256, 256, 0, stream>>>(didx[0], didx[1], didx[2],
                                                             sidx[0], sidx[1], sidx[2],
                                                             cursor, perm);
    const float* srcs[3] = {src0, src1, src2};
    for (int r = 0; r < 3; r++) {
        gemm_kernel<<<1563, 256, 0, stream>>>(srcs[r], Wg[r], hs, N_SRC);
        aggregate_kernel<<<N_DST, 128, 0, stream>>>(hs, elv + r * N_DST, elv + (3 + r) * N_DST,
                                                    perm + (size_t)r * NE, offs + r * (N_DST + 1),
                                                    bg[r], zm, r);
    }
    semantic_kernel<<<4688, 256, 0, stream>>>(zm, sem_W1, sem_b1, sem_W2, wsum);
    finalize_kernel<<<1, 64, 0, stream>>>(wsum, aw, out + (size_t)N_DST * 128);
    combine_kernel<<<6250, 256, 0, stream>>>(zm, aw, out);
}

// Round 2
// 714.521 us; speedup vs baseline: 1.3884x; 1.3884x over previous
//
#include <hip/hip_runtime.h>
#include <math.h>

#define D_DIM 128
#define N_DST 50000
#define N_SRC 50000
#define NE    800000
#define NEG_SLOPE 0.2f

#define NB          196     // coarse buckets: dst>>8, ceil(50000/256)
#define CHUNK       2048    // edges per block in bucket passes
#define NBLK_REL    391     // ceil(NE / CHUNK)

// ---------------------------------------------------------------------------
// wal_r = Wg_r @ al_r,  war_r = Wg_r @ ar_r   (collapses hd GEMM to a matvec)
__global__ void vec_kernel(const float* __restrict__ Wg0, const float* __restrict__ Wg1,
                           const float* __restrict__ Wg2,
                           const float* __restrict__ al0, const float* __restrict__ al1,
                           const float* __restrict__ al2,
                           const float* __restrict__ ar0, const float* __restrict__ ar1,
                           const float* __restrict__ ar2,
                           float* __restrict__ wv) {
    int r = blockIdx.x;
    const float* W  = r == 0 ? Wg0 : (r == 1 ? Wg1 : Wg2);
    const float* al = r == 0 ? al0 : (r == 1 ? al1 : al2);
    const float* ar = r == 0 ? ar0 : (r == 1 ? ar1 : ar2);
    int i = threadIdx.x;
    float sal = 0.f, sar = 0.f;
    for (int j = 0; j < D_DIM; j++) {
        float w = W[i * D_DIM + j];
        sal = fmaf(w, al[j], sal);
        sar = fmaf(w, ar[j], sar);
    }
    wv[r * D_DIM + i]       = sal;
    wv[(3 + r) * D_DIM + i] = sar;
}

// ---------------------------------------------------------------------------
// elv[j][n] = dot(M_j[n,:], wv[j]) ; jobs 0..2 = el (src feats), 3..5 = er (dst)
__global__ void matvec_kernel(const float* __restrict__ src0, const float* __restrict__ src1,
                              const float* __restrict__ src2, const float* __restrict__ dstf,
                              const float* __restrict__ wv, float* __restrict__ elv) {
    int job  = blockIdx.x / 12500;
    int blk  = blockIdx.x % 12500;
    int wave = threadIdx.x >> 6;
    int lane = threadIdx.x & 63;
    int row  = blk * 4 + wave;
    const float* M = job == 0 ? src0 : (job == 1 ? src1 : (job == 2 ? src2 : dstf));
    const float* v = wv + job * D_DIM;
    const float* mr = M + (size_t)row * D_DIM;
    float p = fmaf(mr[lane], v[lane], mr[lane + 64] * v[lane + 64]);
    #pragma unroll
    for (int off = 32; off > 0; off >>= 1) p += __shfl_down(p, off);
    if (lane == 0) elv[job * N_DST + row] = p;
}

// ---------------------------------------------------------------------------
// fp32 GEMM: C[nrows,128] = A[nrows,128] @ W[128,128]
__global__ __launch_bounds__(256) void gemm_kernel(const float* __restrict__ A,
                                                   const float* __restrict__ W,
                                                   float* __restrict__ C, int nrows) {
    __shared__ __align__(16) float As[32][128];
    __shared__ __align__(16) float Ws[32][128];
    int tid  = threadIdx.x;
    int row0 = blockIdx.x * 32;
    int colg = tid & 31, rowg = tid >> 5;
    int col4 = colg * 4;

    #pragma unroll
    for (int j = 0; j < 4; j++) {
        int f4 = tid + j * 256;
        int m = f4 >> 5, k4 = (f4 & 31) * 4;
        int gr = row0 + m; if (gr > nrows - 1) gr = nrows - 1;
        *(float4*)&As[m][k4] = *(const float4*)&A[(size_t)gr * 128 + k4];
    }

    float acc[4][4] = {};
    for (int kb = 0; kb < 4; kb++) {
        #pragma unroll
        for (int j = 0; j < 4; j++) {
            int f4 = tid + j * 256;
            int kk = f4 >> 5, n4 = (f4 & 31) * 4;
            *(float4*)&Ws[kk][n4] = *(const float4*)&W[(size_t)(kb * 32 + kk) * 128 + n4];
        }
        __syncthreads();
        #pragma unroll
        for (int kk = 0; kk < 32; kk += 4) {
            float a_[4][4], w_[4][4];
            #pragma unroll
            for (int r_ = 0; r_ < 4; r_++) {
                float4 t = *(const float4*)&As[rowg * 4 + r_][kb * 32 + kk];
                a_[r_][0] = t.x; a_[r_][1] = t.y; a_[r_][2] = t.z; a_[r_][3] = t.w;
            }
            #pragma unroll
            for (int k_ = 0; k_ < 4; k_++) {
                float4 t = *(const float4*)&Ws[kk + k_][col4];
                w_[k_][0] = t.x; w_[k_][1] = t.y; w_[k_][2] = t.z; w_[k_][3] = t.w;
            }
            #pragma unroll
            for (int k_ = 0; k_ < 4; k_++)
                #pragma unroll
                for (int r_ = 0; r_ < 4; r_++)
                    #pragma unroll
                    for (int c_ = 0; c_ < 4; c_++)
                        acc[r_][c_] = fmaf(a_[r_][k_], w_[k_][c_], acc[r_][c_]);
        }
        __syncthreads();
    }
    #pragma unroll
    for (int r_ = 0; r_ < 4; r_++) {
        int gr = row0 + rowg * 4 + r_;
        if (gr < nrows) {
            float4 t = make_float4(acc[r_][0], acc[r_][1], acc[r_][2], acc[r_][3]);
            *(float4*)&C[(size_t)gr * 128 + col4] = t;
        }
    }
}

// ---------------------------------------------------------------------------
// CSR build, two-level counting sort.
// Pass A: coarse bucket histogram (bucket = dst >> 8)
__global__ __launch_bounds__(256) void bucket_hist_kernel(
        const int* __restrict__ d0, const int* __restrict__ d1, const int* __restrict__ d2,
        int* __restrict__ bucketCnt) {
    __shared__ int cnt[NB];
    int bx = blockIdx.x;
    int r = bx / NBLK_REL, blk = bx % NBLK_REL;
    const int* dd = r == 0 ? d0 : (r == 1 ? d1 : d2);
    int tid = threadIdx.x;
    if (tid < NB) cnt[tid] = 0;
    __syncthreads();
    int e0 = blk * CHUNK, e1 = min(e0 + CHUNK, NE);
    for (int e = e0 + tid; e < e1; e += 256) atomicAdd(&cnt[dd[e] >> 8], 1);
    __syncthreads();
    if (tid < NB && cnt[tid]) atomicAdd(&bucketCnt[r * NB + tid], cnt[tid]);
}

// Pass B: 196-wide exclusive scan per relation -> bucketBase (and cursor copy)
__global__ __launch_bounds__(256) void bucket_scan_kernel(
        const int* __restrict__ bucketCnt, int* __restrict__ bucketBase,
        int* __restrict__ bucketCur) {
    __shared__ int sc[256];
    int r = blockIdx.x, tid = threadIdx.x;
    int v = tid < NB ? bucketCnt[r * NB + tid] : 0;
    sc[tid] = v;
    __syncthreads();
    for (int off = 1; off < 256; off <<= 1) {
        int t = tid >= off ? sc[tid - off] : 0;
        __syncthreads();
        sc[tid] += t;
        __syncthreads();
    }
    int excl = sc[tid] - v;
    if (tid < NB) { bucketBase[r * (NB + 1) + tid] = excl; bucketCur[r * NB + tid] = excl; }
    if (tid == 255) bucketBase[r * (NB + 1) + NB] = sc[255];
}

// Pass C: scatter (src,dst) pairs into coarse-bucket-grouped array.
// Per-block LDS ranks + one global atomic per (block,bucket) -> contiguous runs.
__global__ __launch_bounds__(256) void bucket_scatter_kernel(
        const int* __restrict__ d0, const int* __restrict__ d1, const int* __restrict__ d2,
        const int* __restrict__ s0, const int* __restrict__ s1, const int* __restrict__ s2,
        int* __restrict__ bucketCur, int2* __restrict__ pairs) {
    __shared__ int cnt[NB], base[NB], cur[NB];
    int bx = blockIdx.x;
    int r = bx / NBLK_REL, blk = bx % NBLK_REL;
    const int* dd = r == 0 ? d0 : (r == 1 ? d1 : d2);
    const int* ss = r == 0 ? s0 : (r == 1 ? s1 : s2);
    int tid = threadIdx.x;
    if (tid < NB) { cnt[tid] = 0; cur[tid] = 0; }
    __syncthreads();
    int e0 = blk * CHUNK, e1 = min(e0 + CHUNK, NE);
    for (int e = e0 + tid; e < e1; e += 256) atomicAdd(&cnt[dd[e] >> 8], 1);
    __syncthreads();
    if (tid < NB) base[tid] = cnt[tid] ? atomicAdd(&bucketCur[r * NB + tid], cnt[tid]) : 0;
    __syncthreads();
    int2* pr = pairs + (size_t)r * NE;
    for (int e = e0 + tid; e < e1; e += 256) {
        int d = dd[e], b = d >> 8;
        int rank = atomicAdd(&cur[b], 1);
        pr[base[b] + rank] = make_int2(ss[e], d);
    }
}

// Pass D: per-bucket fine CSR. One block owns one bucket (256 dst, ~4K edges,
// 16KB contiguous perm region -> single-XCD write-back, no amplification).
__global__ __launch_bounds__(256) void csr_kernel(
        const int2* __restrict__ pairs, const int* __restrict__ bucketBase,
        int* __restrict__ offs, int* __restrict__ cnts, int* __restrict__ perm) {
    __shared__ int hist[256], sc[256], cur[256];
    int bx = blockIdx.x;
    int r = bx / NB, b = bx % NB;
    int tid = threadIdx.x;
    int seg0 = bucketBase[r * (NB + 1) + b];
    int seg1 = bucketBase[r * (NB + 1) + b + 1];
    int nE = seg1 - seg0;
    const int2* pr = pairs + (size_t)r * NE + seg0;
    hist[tid] = 0;
    __syncthreads();
    for (int i = tid; i < nE; i += 256) atomicAdd(&hist[pr[i].y & 255], 1);
    __syncthreads();
    int v = hist[tid];
    sc[tid] = v;
    __syncthreads();
    for (int off = 1; off < 256; off <<= 1) {
        int t = tid >= off ? sc[tid - off] : 0;
        __syncthreads();
        sc[tid] += t;
        __syncthreads();
    }
    int excl = sc[tid] - v;
    int dstg = b * 256 + tid;
    if (dstg < N_DST) { offs[r * N_DST + dstg] = seg0 + excl; cnts[r * N_DST + dstg] = v; }
    cur[tid] = excl;
    __syncthreads();
    int* pm = perm + (size_t)r * NE + seg0;
    for (int i = tid; i < nE; i += 256) {
        int2 p = pr[i];
        int rank = atomicAdd(&cur[p.y & 255], 1);
        pm[rank] = p.x;
    }
}

// ---------------------------------------------------------------------------
// per-dst edge softmax + weighted feature aggregation (+ bias + elu)
__global__ __launch_bounds__(128) void aggregate_kernel(
        const float* __restrict__ hs, const float* __restrict__ el,
        const float* __restrict__ er, const int* __restrict__ perm,
        const int* __restrict__ offs, const int* __restrict__ cnts,
        const float* __restrict__ bg, float* __restrict__ zm, int r) {
    __shared__ float wsh[128];
    __shared__ int   ssh[128];
    __shared__ float red[2];
    int b = blockIdx.x, tid = threadIdx.x;
    int o0 = offs[b], deg = cnts[b];
    float erb = er[b];

    float lmax = -INFINITY;
    for (int i = tid; i < deg; i += 128) {
        int s = perm[o0 + i];
        float x = el[s] + erb;
        x = x >= 0.f ? x : NEG_SLOPE * x;
        lmax = fmaxf(lmax, x);
    }
    #pragma unroll
    for (int off = 32; off > 0; off >>= 1) lmax = fmaxf(lmax, __shfl_down(lmax, off));
    if ((tid & 63) == 0) red[tid >> 6] = lmax;
    __syncthreads();
    float m = fmaxf(red[0], red[1]);
    __syncthreads();

    float lsum = 0.f;
    for (int i = tid; i < deg; i += 128) {
        int s = perm[o0 + i];
        float x = el[s] + erb;
        x = x >= 0.f ? x : NEG_SLOPE * x;
        lsum += expf(x - m);
    }
    #pragma unroll
    for (int off = 32; off > 0; off >>= 1) lsum += __shfl_down(lsum, off);
    if ((tid & 63) == 0) red[tid >> 6] = lsum;
    __syncthreads();
    float zsum = red[0] + red[1];
    float invz = deg > 0 ? 1.f / zsum : 0.f;

    float acc = 0.f;
    for (int c0 = 0; c0 < deg; c0 += 128) {
        int n = min(128, deg - c0);
        __syncthreads();
        if (tid < n) {
            int s = perm[o0 + c0 + tid];
            float x = el[s] + erb;
            x = x >= 0.f ? x : NEG_SLOPE * x;
            wsh[tid] = expf(x - m) * invz;
            ssh[tid] = s;
        }
        __syncthreads();
        int j = 0;
        for (; j + 4 <= n; j += 4) {
            float w0 = wsh[j], w1 = wsh[j+1], w2 = wsh[j+2], w3 = wsh[j+3];
            int   s0 = ssh[j], s1 = ssh[j+1], s2 = ssh[j+2], s3 = ssh[j+3];
            float h0 = hs[(size_t)s0 * 128 + tid];
            float h1 = hs[(size_t)s1 * 128 + tid];
            float h2 = hs[(size_t)s2 * 128 + tid];
            float h3 = hs[(size_t)s3 * 128 + tid];
            acc = fmaf(w0, h0, acc); acc = fmaf(w1, h1, acc);
            acc = fmaf(w2, h2, acc); acc = fmaf(w3, h3, acc);
        }
        for (; j < n; j++) acc = fmaf(wsh[j], hs[(size_t)ssh[j] * 128 + tid], acc);
    }
    float z = acc + bg[tid];
    z = z > 0.f ? z : expm1f(z);
    zm[((size_t)b * 3 + r) * 128 + tid] = z;
}

// ---------------------------------------------------------------------------
// semantic attention: h[n,r] = tanh(zm[n,r,:]@W1 + b1) @ W2 summed into w_sum[3]
__global__ __launch_bounds__(256) void semantic_kernel(const float* __restrict__ A,
                                                       const float* __restrict__ W1,
                                                       const float* __restrict__ b1,
                                                       const float* __restrict__ W2,
                                                       float* __restrict__ w_sum) {
    __shared__ __align__(16) float As[32][128];
    __shared__ __align__(16) float Ws[32][128];
    __shared__ float hsum[3];
    const int nrows = N_DST * 3;
    int tid  = threadIdx.x;
    if (tid < 3) hsum[tid] = 0.f;
    int row0 = blockIdx.x * 32;
    int colg = tid & 31, rowg = tid >> 5;
    int col4 = colg * 4;

    #pragma unroll
    for (int j = 0; j < 4; j++) {
        int f4 = tid + j * 256;
        int m = f4 >> 5, k4 = (f4 & 31) * 4;
        int gr = row0 + m; if (gr > nrows - 1) gr = nrows - 1;
        *(float4*)&As[m][k4] = *(const float4*)&A[(size_t)gr * 128 + k4];
    }

    float acc[4][4] = {};
    for (int kb = 0; kb < 4; kb++) {
        #pragma unroll
        for (int j = 0; j < 4; j++) {
            int f4 = tid + j * 256;
            int kk = f4 >> 5, n4 = (f4 & 31) * 4;
            *(float4*)&Ws[kk][n4] = *(const float4*)&W1[(size_t)(kb * 32 + kk) * 128 + n4];
        }
        __syncthreads();
        #pragma unroll
        for (int kk = 0; kk < 32; kk += 4) {
            float a_[4][4], w_[4][4];
            #pragma unroll
            for (int r_ = 0; r_ < 4; r_++) {
                float4 t = *(const float4*)&As[rowg * 4 + r_][kb * 32 + kk];
                a_[r_][0] = t.x; a_[r_][1] = t.y; a_[r_][2] = t.z; a_[r_][3] = t.w;
            }
            #pragma unroll
            for (int k_ = 0; k_ < 4; k_++) {
                float4 t = *(const float4*)&Ws[kk + k_][col4];
                w_[k_][0] = t.x; w_[k_][1] = t.y; w_[k_][2] = t.z; w_[k_][3] = t.w;
            }
            #pragma unroll
            for (int k_ = 0; k_ < 4; k_++)
                #pragma unroll
                for (int r_ = 0; r_ < 4; r_++)
                    #pragma unroll
                    for (int c_ = 0; c_ < 4; c_++)
                        acc[r_][c_] = fmaf(a_[r_][k_], w_[k_][c_], acc[r_][c_]);
        }
        __syncthreads();
    }

    float4 b1v = *(const float4*)&b1[col4];
    float4 w2v = *(const float4*)&W2[col4];
    float bb[4] = {b1v.x, b1v.y, b1v.z, b1v.w};
    float ww[4] = {w2v.x, w2v.y, w2v.z, w2v.w};
    float part[4];
    #pragma unroll
    for (int r_ = 0; r_ < 4; r_++) {
        float s = 0.f;
        #pragma unroll
        for (int c_ = 0; c_ < 4; c_++)
            s = fmaf(tanhf(acc[r_][c_] + bb[c_]), ww[c_], s);
        part[r_] = s;
    }
    #pragma unroll
    for (int m_ = 16; m_ > 0; m_ >>= 1)
        #pragma unroll
        for (int r_ = 0; r_ < 4; r_++) part[r_] += __shfl_xor(part[r_], m_);
    if (colg == 0) {
        #pragma unroll
        for (int r_ = 0; r_ < 4; r_++) {
            int gr = row0 + rowg * 4 + r_;
            if (gr < nrows) atomicAdd(&hsum[gr % 3], part[r_]);
        }
    }
    __syncthreads();
    if (tid < 3) atomicAdd(&w_sum[tid], hsum[tid]);
}

// ---------------------------------------------------------------------------
__global__ void finalize_kernel(const float* __restrict__ w_sum, float* __restrict__ aw,
                                float* __restrict__ out_att) {
    if (threadIdx.x == 0 && blockIdx.x == 0) {
        float w0 = w_sum[0] / (float)N_DST;
        float w1 = w_sum[1] / (float)N_DST;
        float w2 = w_sum[2] / (float)N_DST;
        float m = fmaxf(w0, fmaxf(w1, w2));
        float e0 = expf(w0 - m), e1 = expf(w1 - m), e2 = expf(w2 - m);
        float s = e0 + e1 + e2;
        aw[0] = e0 / s; aw[1] = e1 / s; aw[2] = e2 / s;
        out_att[0] = aw[0]; out_att[1] = aw[1]; out_att[2] = aw[2];
    }
}

__global__ void combine_kernel(const float* __restrict__ zm, const float* __restrict__ aw,
                               float* __restrict__ out) {
    int id4 = blockIdx.x * 256 + threadIdx.x;
    float a0 = aw[0], a1 = aw[1], a2 = aw[2];
    int n  = id4 >> 5;
    int d4 = (id4 & 31) * 4;
    const float4 z0 = *(const float4*)&zm[((size_t)n * 3 + 0) * 128 + d4];
    const float4 z1 = *(const float4*)&zm[((size_t)n * 3 + 1) * 128 + d4];
    const float4 z2 = *(const float4*)&zm[((size_t)n * 3 + 2) * 128 + d4];
    float4 o;
    o.x = a0 * z0.x + a1 * z1.x + a2 * z2.x;
    o.y = a0 * z0.y + a1 * z1.y + a2 * z2.y;
    o.z = a0 * z0.z + a1 * z1.z + a2 * z2.z;
    o.w = a0 * z0.w + a1 * z1.w + a2 * z2.w;
    *(float4*)&out[(size_t)n * 128 + d4] = o;
}

// ---------------------------------------------------------------------------
extern "C" void kernel_launch(void* const* d_in, const int* in_sizes, int n_in,
                              void* d_out, int out_size, void* d_ws, size_t ws_size,
                              hipStream_t stream) {
    const float* dstf   = (const float*)d_in[0];
    const float* src0   = (const float*)d_in[1];
    const float* src1   = (const float*)d_in[2];
    const float* src2   = (const float*)d_in[3];
    const float* sem_W1 = (const float*)d_in[4];
    const float* sem_b1 = (const float*)d_in[5];
    const float* sem_W2 = (const float*)d_in[6];
    const float* Wg[3]  = {(const float*)d_in[7],  (const float*)d_in[13], (const float*)d_in[19]};
    const float* al[3]  = {(const float*)d_in[8],  (const float*)d_in[14], (const float*)d_in[20]};
    const float* ar[3]  = {(const float*)d_in[9],  (const float*)d_in[15], (const float*)d_in[21]};
    const float* bg[3]  = {(const float*)d_in[10], (const float*)d_in[16], (const float*)d_in[22]};
    const int*  sidx[3] = {(const int*)d_in[11], (const int*)d_in[17], (const int*)d_in[23]};
    const int*  didx[3] = {(const int*)d_in[12], (const int*)d_in[18], (const int*)d_in[24]};
    float* out = (float*)d_out;

    char* p = (char*)d_ws;
    auto alloc = [&](size_t bytes) -> char* {
        char* q = p; p += (bytes + 255) & ~(size_t)255; return q;
    };
    float* zm     = (float*)alloc((size_t)N_DST * 3 * 128 * 4);   // 76.8 MB
    float* hs     = (float*)alloc((size_t)N_SRC * 128 * 4);       // 25.6 MB; pairs aliases (dead before gemm)
    float* elv    = (float*)alloc((size_t)6 * N_DST * 4);
    float* wv     = (float*)alloc((size_t)6 * 128 * 4);
    float* wsum   = (float*)alloc((size_t)16 * 4);
    float* aw     = wsum + 8;
    int*   cnts   = (int*)alloc((size_t)3 * N_DST * 4);
    int*   offs   = (int*)alloc((size_t)3 * N_DST * 4);
    int*   perm   = (int*)alloc((size_t)3 * NE * 4);              // 9.6 MB
    int*   bucketCnt  = (int*)alloc((size_t)3 * NB * 4);
    int*   bucketBase = (int*)alloc((size_t)3 * (NB + 1) * 4);
    int*   bucketCur  = (int*)alloc((size_t)3 * NB * 4);
    int2*  pairs  = (int2*)hs;                                    // 19.2 MB alias

    hipMemsetAsync(bucketCnt, 0, (size_t)3 * NB * 4, stream);
    hipMemsetAsync(wsum, 0, (size_t)16 * 4, stream);

    vec_kernel<<<3, 128, 0, stream>>>(Wg[0], Wg[1], Wg[2], al[0], al[1], al[2],
                                      ar[0], ar[1], ar[2], wv);
    matvec_kernel<<<75000, 256, 0, stream>>>(src0, src1, src2, dstf, wv, elv);

    bucket_hist_kernel<<<3 * NBLK_REL, 256, 0, stream>>>(didx[0], didx[1], didx[2], bucketCnt);
    bucket_scan_kernel<<<3, 256, 0, stream>>>(bucketCnt, bucketBase, bucketCur);
    bucket_scatter_kernel<<<3 * NBLK_REL, 256, 0, stream>>>(didx[0], didx[1], didx[2],
                                                            sidx[0], sidx[1], sidx[2],
                                                            bucketCur, pairs);
    csr_kernel<<<3 * NB, 256, 0, stream>>>(pairs, bucketBase, offs, cnts, perm);

    const float* srcs[3] = {src0, src1, src2};
    for (int r = 0; r < 3; r++) {
        gemm_kernel<<<1563, 256, 0, stream>>>(srcs[r], Wg[r], hs, N_SRC);
        aggregate_kernel<<<N_DST, 128, 0, stream>>>(hs, elv + r * N_DST, elv + (3 + r) * N_DST,
                                                    perm + (size_t)r * NE, offs + r * N_DST,
                                                    cnts + r * N_DST, bg[r], zm, r);
    }
    semantic_kernel<<<4688, 256, 0, stream>>>(zm, sem_W1, sem_b1, sem_W2, wsum);
    finalize_kernel<<<1, 64, 0, stream>>>(wsum, aw, out + (size_t)N_DST * 128);
    combine_kernel<<<6250, 256, 0, stream>>>(zm, aw, out);
}

// Round 3
// 643.326 us; speedup vs baseline: 1.5420x; 1.1107x over previous
//
#include <hip/hip_runtime.h>
#include <math.h>

#define D_DIM 128
#define N_DST 50000
#define N_SRC 50000
#define NE    800000
#define NEG_SLOPE 0.2f

#define NB          196     // coarse buckets: dst>>8
#define CHUNK       2048
#define NBLK_REL    391     // ceil(NE / CHUNK)
#define GEMM_BLKS   1563    // ceil(N_SRC / 32)

typedef unsigned short ushort_t;
using f32x4  = __attribute__((ext_vector_type(4))) float;
using bf16x8 = __attribute__((ext_vector_type(8))) short;

__device__ __forceinline__ ushort_t f2bf(float x) {
    unsigned u = __float_as_uint(x);
    unsigned r = (u + 0x7fffu + ((u >> 16) & 1u)) >> 16;
    return (ushort_t)r;
}
__device__ __forceinline__ float bf2f(ushort_t b) {
    return __uint_as_float(((unsigned)b) << 16);
}
__device__ __forceinline__ float tanh_fast(float x) {
    float e = __expf(2.f * x);
    return 1.f - 2.f / (e + 1.f);
}

// ---------------------------------------------------------------------------
// wal_r = Wg_r @ al_r,  war_r = Wg_r @ ar_r
__global__ void vec_kernel(const float* __restrict__ Wg0, const float* __restrict__ Wg1,
                           const float* __restrict__ Wg2,
                           const float* __restrict__ al0, const float* __restrict__ al1,
                           const float* __restrict__ al2,
                           const float* __restrict__ ar0, const float* __restrict__ ar1,
                           const float* __restrict__ ar2,
                           float* __restrict__ wv) {
    int r = blockIdx.x;
    const float* W  = r == 0 ? Wg0 : (r == 1 ? Wg1 : Wg2);
    const float* al = r == 0 ? al0 : (r == 1 ? al1 : al2);
    const float* ar = r == 0 ? ar0 : (r == 1 ? ar1 : ar2);
    int i = threadIdx.x;
    float sal = 0.f, sar = 0.f;
    for (int j = 0; j < D_DIM; j++) {
        float w = W[i * D_DIM + j];
        sal = fmaf(w, al[j], sal);
        sar = fmaf(w, ar[j], sar);
    }
    wv[r * D_DIM + i]       = sal;
    wv[(3 + r) * D_DIM + i] = sar;
}

// ---------------------------------------------------------------------------
__global__ void matvec_kernel(const float* __restrict__ src0, const float* __restrict__ src1,
                              const float* __restrict__ src2, const float* __restrict__ dstf,
                              const float* __restrict__ wv, float* __restrict__ elv) {
    int job  = blockIdx.x / 12500;
    int blk  = blockIdx.x % 12500;
    int wave = threadIdx.x >> 6;
    int lane = threadIdx.x & 63;
    int row  = blk * 4 + wave;
    const float* M = job == 0 ? src0 : (job == 1 ? src1 : (job == 2 ? src2 : dstf));
    const float* v = wv + job * D_DIM;
    const float* mr = M + (size_t)row * D_DIM;
    float p = fmaf(mr[lane], v[lane], mr[lane + 64] * v[lane + 64]);
    #pragma unroll
    for (int off = 32; off > 0; off >>= 1) p += __shfl_down(p, off);
    if (lane == 0) elv[job * N_DST + row] = p;
}

// ---------------------------------------------------------------------------
// fused fp32 GEMM, all 3 relations: hs_r[n,:] = bf16( src_r[n,:] @ Wg_r )
__global__ __launch_bounds__(256) void gemm_kernel(
        const float* __restrict__ A0, const float* __restrict__ A1, const float* __restrict__ A2,
        const float* __restrict__ W0, const float* __restrict__ W1, const float* __restrict__ W2,
        ushort_t* __restrict__ hs) {
    __shared__ __align__(16) float As[32][128];
    __shared__ __align__(16) float Ws[32][128];
    int rel = blockIdx.x / GEMM_BLKS, blk = blockIdx.x % GEMM_BLKS;
    const float* A = rel == 0 ? A0 : (rel == 1 ? A1 : A2);
    const float* W = rel == 0 ? W0 : (rel == 1 ? W1 : W2);
    ushort_t* C = hs + (size_t)rel * N_SRC * 128;
    int tid  = threadIdx.x;
    int row0 = blk * 32;
    int colg = tid & 31, rowg = tid >> 5;
    int col4 = colg * 4;

    #pragma unroll
    for (int j = 0; j < 4; j++) {
        int f4 = tid + j * 256;
        int m = f4 >> 5, k4 = (f4 & 31) * 4;
        int gr = row0 + m; if (gr > N_SRC - 1) gr = N_SRC - 1;
        *(float4*)&As[m][k4] = *(const float4*)&A[(size_t)gr * 128 + k4];
    }

    float acc[4][4] = {};
    for (int kb = 0; kb < 4; kb++) {
        #pragma unroll
        for (int j = 0; j < 4; j++) {
            int f4 = tid + j * 256;
            int kk = f4 >> 5, n4 = (f4 & 31) * 4;
            *(float4*)&Ws[kk][n4] = *(const float4*)&W[(size_t)(kb * 32 + kk) * 128 + n4];
        }
        __syncthreads();
        #pragma unroll
        for (int kk = 0; kk < 32; kk += 4) {
            float a_[4][4], w_[4][4];
            #pragma unroll
            for (int r_ = 0; r_ < 4; r_++) {
                float4 t = *(const float4*)&As[rowg * 4 + r_][kb * 32 + kk];
                a_[r_][0] = t.x; a_[r_][1] = t.y; a_[r_][2] = t.z; a_[r_][3] = t.w;
            }
            #pragma unroll
            for (int k_ = 0; k_ < 4; k_++) {
                float4 t = *(const float4*)&Ws[kk + k_][col4];
                w_[k_][0] = t.x; w_[k_][1] = t.y; w_[k_][2] = t.z; w_[k_][3] = t.w;
            }
            #pragma unroll
            for (int k_ = 0; k_ < 4; k_++)
                #pragma unroll
                for (int r_ = 0; r_ < 4; r_++)
                    #pragma unroll
                    for (int c_ = 0; c_ < 4; c_++)
                        acc[r_][c_] = fmaf(a_[r_][k_], w_[k_][c_], acc[r_][c_]);
        }
        __syncthreads();
    }
    #pragma unroll
    for (int r_ = 0; r_ < 4; r_++) {
        int gr = row0 + rowg * 4 + r_;
        if (gr < N_SRC) {
            ushort4 t = make_ushort4(f2bf(acc[r_][0]), f2bf(acc[r_][1]),
                                     f2bf(acc[r_][2]), f2bf(acc[r_][3]));
            *(ushort4*)&C[(size_t)gr * 128 + col4] = t;
        }
    }
}

// ---------------------------------------------------------------------------
// CSR build (two-level counting sort)
__global__ __launch_bounds__(256) void bucket_hist_kernel(
        const int* __restrict__ d0, const int* __restrict__ d1, const int* __restrict__ d2,
        int* __restrict__ bucketCnt) {
    __shared__ int cnt[NB];
    int bx = blockIdx.x;
    int r = bx / NBLK_REL, blk = bx % NBLK_REL;
    const int* dd = r == 0 ? d0 : (r == 1 ? d1 : d2);
    int tid = threadIdx.x;
    if (tid < NB) cnt[tid] = 0;
    __syncthreads();
    int e0 = blk * CHUNK, e1 = min(e0 + CHUNK, NE);
    for (int e = e0 + tid; e < e1; e += 256) atomicAdd(&cnt[dd[e] >> 8], 1);
    __syncthreads();
    if (tid < NB && cnt[tid]) atomicAdd(&bucketCnt[r * NB + tid], cnt[tid]);
}

__global__ __launch_bounds__(256) void bucket_scan_kernel(
        const int* __restrict__ bucketCnt, int* __restrict__ bucketBase,
        int* __restrict__ bucketCur) {
    __shared__ int sc[256];
    int r = blockIdx.x, tid = threadIdx.x;
    int v = tid < NB ? bucketCnt[r * NB + tid] : 0;
    sc[tid] = v;
    __syncthreads();
    for (int off = 1; off < 256; off <<= 1) {
        int t = tid >= off ? sc[tid - off] : 0;
        __syncthreads();
        sc[tid] += t;
        __syncthreads();
    }
    int excl = sc[tid] - v;
    if (tid < NB) { bucketBase[r * (NB + 1) + tid] = excl; bucketCur[r * NB + tid] = excl; }
    if (tid == 255) bucketBase[r * (NB + 1) + NB] = sc[255];
}

__global__ __launch_bounds__(256) void bucket_scatter_kernel(
        const int* __restrict__ d0, const int* __restrict__ d1, const int* __restrict__ d2,
        const int* __restrict__ s0, const int* __restrict__ s1, const int* __restrict__ s2,
        int* __restrict__ bucketCur, int2* __restrict__ pairs) {
    __shared__ int cnt[NB], base[NB], cur[NB];
    int bx = blockIdx.x;
    int r = bx / NBLK_REL, blk = bx % NBLK_REL;
    const int* dd = r == 0 ? d0 : (r == 1 ? d1 : d2);
    const int* ss = r == 0 ? s0 : (r == 1 ? s1 : s2);
    int tid = threadIdx.x;
    if (tid < NB) { cnt[tid] = 0; cur[tid] = 0; }
    __syncthreads();
    int e0 = blk * CHUNK, e1 = min(e0 + CHUNK, NE);
    for (int e = e0 + tid; e < e1; e += 256) atomicAdd(&cnt[dd[e] >> 8], 1);
    __syncthreads();
    if (tid < NB) base[tid] = cnt[tid] ? atomicAdd(&bucketCur[r * NB + tid], cnt[tid]) : 0;
    __syncthreads();
    int2* pr = pairs + (size_t)r * NE;
    for (int e = e0 + tid; e < e1; e += 256) {
        int d = dd[e], b = d >> 8;
        int rank = atomicAdd(&cur[b], 1);
        pr[base[b] + rank] = make_int2(ss[e], d);
    }
}

__global__ __launch_bounds__(256) void csr_kernel(
        const int2* __restrict__ pairs, const int* __restrict__ bucketBase,
        int* __restrict__ offs, int* __restrict__ cnts, int* __restrict__ perm) {
    __shared__ int hist[256], sc[256], cur[256];
    int bx = blockIdx.x;
    int r = bx / NB, b = bx % NB;
    int tid = threadIdx.x;
    int seg0 = bucketBase[r * (NB + 1) + b];
    int seg1 = bucketBase[r * (NB + 1) + b + 1];
    int nE = seg1 - seg0;
    const int2* pr = pairs + (size_t)r * NE + seg0;
    hist[tid] = 0;
    __syncthreads();
    for (int i = tid; i < nE; i += 256) atomicAdd(&hist[pr[i].y & 255], 1);
    __syncthreads();
    int v = hist[tid];
    sc[tid] = v;
    __syncthreads();
    for (int off = 1; off < 256; off <<= 1) {
        int t = tid >= off ? sc[tid - off] : 0;
        __syncthreads();
        sc[tid] += t;
        __syncthreads();
    }
    int excl = sc[tid] - v;
    int dstg = b * 256 + tid;
    if (dstg < N_DST) { offs[r * N_DST + dstg] = seg0 + excl; cnts[r * N_DST + dstg] = v; }
    cur[tid] = excl;
    __syncthreads();
    int* pm = perm + (size_t)r * NE + seg0;
    for (int i = tid; i < nE; i += 256) {
        int2 p = pr[i];
        int rank = atomicAdd(&cur[p.y & 255], 1);
        pm[rank] = p.x;
    }
}

// ---------------------------------------------------------------------------
// fused edge softmax + aggregation, all 3 relations (hs is bf16)
__global__ __launch_bounds__(128) void aggregate_kernel(
        const ushort_t* __restrict__ hs, const float* __restrict__ elv,
        const int* __restrict__ perm, const int* __restrict__ offs,
        const int* __restrict__ cnts,
        const float* __restrict__ bg0, const float* __restrict__ bg1,
        const float* __restrict__ bg2, float* __restrict__ zm) {
    __shared__ float wsh[128];
    __shared__ int   ssh[128];
    __shared__ float red[2];
    int bx = blockIdx.x;
    int rel = bx / N_DST, b = bx - rel * N_DST;
    int tid = threadIdx.x;
    const float* el = elv + rel * N_DST;
    float erb = elv[(3 + rel) * N_DST + b];
    const float* bg = rel == 0 ? bg0 : (rel == 1 ? bg1 : bg2);
    const int* pm = perm + (size_t)rel * NE;
    const ushort_t* hsr = hs + (size_t)rel * N_SRC * 128;
    int o0 = offs[rel * N_DST + b], deg = cnts[rel * N_DST + b];

    float lmax = -INFINITY;
    for (int i = tid; i < deg; i += 128) {
        int s = pm[o0 + i];
        float x = el[s] + erb;
        x = x >= 0.f ? x : NEG_SLOPE * x;
        lmax = fmaxf(lmax, x);
    }
    #pragma unroll
    for (int off = 32; off > 0; off >>= 1) lmax = fmaxf(lmax, __shfl_down(lmax, off));
    if ((tid & 63) == 0) red[tid >> 6] = lmax;
    __syncthreads();
    float m = fmaxf(red[0], red[1]);
    __syncthreads();

    float lsum = 0.f;
    for (int i = tid; i < deg; i += 128) {
        int s = pm[o0 + i];
        float x = el[s] + erb;
        x = x >= 0.f ? x : NEG_SLOPE * x;
        lsum += expf(x - m);
    }
    #pragma unroll
    for (int off = 32; off > 0; off >>= 1) lsum += __shfl_down(lsum, off);
    if ((tid & 63) == 0) red[tid >> 6] = lsum;
    __syncthreads();
    float zsum = red[0] + red[1];
    float invz = deg > 0 ? 1.f / zsum : 0.f;

    float acc = 0.f;
    for (int c0 = 0; c0 < deg; c0 += 128) {
        int n = min(128, deg - c0);
        __syncthreads();
        if (tid < n) {
            int s = pm[o0 + c0 + tid];
            float x = el[s] + erb;
            x = x >= 0.f ? x : NEG_SLOPE * x;
            wsh[tid] = expf(x - m) * invz;
            ssh[tid] = s;
        }
        __syncthreads();
        int j = 0;
        for (; j + 4 <= n; j += 4) {
            float w0 = wsh[j], w1 = wsh[j+1], w2 = wsh[j+2], w3 = wsh[j+3];
            int   s0 = ssh[j], s1 = ssh[j+1], s2 = ssh[j+2], s3 = ssh[j+3];
            float h0 = bf2f(hsr[(size_t)s0 * 128 + tid]);
            float h1 = bf2f(hsr[(size_t)s1 * 128 + tid]);
            float h2 = bf2f(hsr[(size_t)s2 * 128 + tid]);
            float h3 = bf2f(hsr[(size_t)s3 * 128 + tid]);
            acc = fmaf(w0, h0, acc); acc = fmaf(w1, h1, acc);
            acc = fmaf(w2, h2, acc); acc = fmaf(w3, h3, acc);
        }
        for (; j < n; j++) acc = fmaf(wsh[j], bf2f(hsr[(size_t)ssh[j] * 128 + tid]), acc);
    }
    float z = acc + bg[tid];
    z = z > 0.f ? z : expm1f(z);
    zm[((size_t)b * 3 + rel) * 128 + tid] = z;
}

// ---------------------------------------------------------------------------
// semantic attention via bf16 MFMA: w_sum[r] += sum_n tanh(zm[n,r,:]@W1+b1)@W2
// block = 256 (4 waves), 64 rows/block, full N=128, K=128
__global__ __launch_bounds__(256) void semantic_kernel(
        const float* __restrict__ zm, const float* __restrict__ W1,
        const float* __restrict__ b1, const float* __restrict__ W2,
        float* __restrict__ w_sum) {
    __shared__ ushort_t Wt[128 * 136];   // Wt[n][k] = bf16(W1[k][n]), stride 136 (pad)
    __shared__ float hsum[3];
    const int NROWS = N_DST * 3;
    int tid = threadIdx.x;
    if (tid < 3) hsum[tid] = 0.f;

    // stage W1 transposed as bf16 (once per block)
    #pragma unroll
    for (int i = 0; i < 16; i++) {
        int p = i * 256 + tid;          // 4096 groups of 4 k-elems
        int n = p & 127, kq = p >> 7;   // kq in [0,32)
        int k = kq * 4;
        ushort4 t = make_ushort4(f2bf(W1[(size_t)(k + 0) * 128 + n]),
                                 f2bf(W1[(size_t)(k + 1) * 128 + n]),
                                 f2bf(W1[(size_t)(k + 2) * 128 + n]),
                                 f2bf(W1[(size_t)(k + 3) * 128 + n]));
        *(ushort4*)&Wt[n * 136 + k] = t;
    }
    __syncthreads();

    int w    = tid >> 6, lane = tid & 63;
    int quad = lane >> 4, l15 = lane & 15;
    long row0 = (long)blockIdx.x * 64 + w * 16;     // this wave's 16 rows
    long rA = row0 + l15; if (rA > NROWS - 1) rA = NROWS - 1;

    f32x4 acc[8] = {};
    #pragma unroll
    for (int kc = 0; kc < 4; kc++) {
        int k0 = kc * 32 + quad * 8;
        const float* src = zm + (size_t)rA * 128 + k0;
        float4 f0 = *(const float4*)src;
        float4 f1 = *(const float4*)(src + 4);
        bf16x8 a;
        a[0] = (short)f2bf(f0.x); a[1] = (short)f2bf(f0.y);
        a[2] = (short)f2bf(f0.z); a[3] = (short)f2bf(f0.w);
        a[4] = (short)f2bf(f1.x); a[5] = (short)f2bf(f1.y);
        a[6] = (short)f2bf(f1.z); a[7] = (short)f2bf(f1.w);
        #pragma unroll
        for (int nt = 0; nt < 8; nt++) {
            int n = nt * 16 + l15;
            bf16x8 bfr = *(const bf16x8*)&Wt[n * 136 + k0];
            acc[nt] = __builtin_amdgcn_mfma_f32_16x16x32_bf16(a, bfr, acc[nt], 0, 0, 0);
        }
    }

    // epilogue: tanh + dot(W2) per row, reduce over the 16 col-lanes
    float part[4] = {0.f, 0.f, 0.f, 0.f};
    #pragma unroll
    for (int nt = 0; nt < 8; nt++) {
        int n = nt * 16 + l15;
        float bb = b1[n], ww = W2[n];
        #pragma unroll
        for (int i = 0; i < 4; i++) {
            float t = tanh_fast(acc[nt][i] + bb);
            part[i] = fmaf(t, ww, part[i]);
        }
    }
    #pragma unroll
    for (int msk = 1; msk < 16; msk <<= 1)
        #pragma unroll
        for (int i = 0; i < 4; i++) part[i] += __shfl_xor(part[i], msk);
    if (l15 == 0) {
        #pragma unroll
        for (int i = 0; i < 4; i++) {
            long R = row0 + quad * 4 + i;
            if (R < NROWS) atomicAdd(&hsum[(int)(R % 3)], part[i]);
        }
    }
    __syncthreads();
    if (tid < 3) atomicAdd(&w_sum[tid], hsum[tid]);
}

// ---------------------------------------------------------------------------
__global__ void finalize_kernel(const float* __restrict__ w_sum, float* __restrict__ aw,
                                float* __restrict__ out_att) {
    if (threadIdx.x == 0 && blockIdx.x == 0) {
        float w0 = w_sum[0] / (float)N_DST;
        float w1 = w_sum[1] / (float)N_DST;
        float w2 = w_sum[2] / (float)N_DST;
        float m = fmaxf(w0, fmaxf(w1, w2));
        float e0 = expf(w0 - m), e1 = expf(w1 - m), e2 = expf(w2 - m);
        float s = e0 + e1 + e2;
        aw[0] = e0 / s; aw[1] = e1 / s; aw[2] = e2 / s;
        out_att[0] = aw[0]; out_att[1] = aw[1]; out_att[2] = aw[2];
    }
}

__global__ void combine_kernel(const float* __restrict__ zm, const float* __restrict__ aw,
                               float* __restrict__ out) {
    int id4 = blockIdx.x * 256 + threadIdx.x;
    float a0 = aw[0], a1 = aw[1], a2 = aw[2];
    int n  = id4 >> 5;
    int d4 = (id4 & 31) * 4;
    const float4 z0 = *(const float4*)&zm[((size_t)n * 3 + 0) * 128 + d4];
    const float4 z1 = *(const float4*)&zm[((size_t)n * 3 + 1) * 128 + d4];
    const float4 z2 = *(const float4*)&zm[((size_t)n * 3 + 2) * 128 + d4];
    float4 o;
    o.x = a0 * z0.x + a1 * z1.x + a2 * z2.x;
    o.y = a0 * z0.y + a1 * z1.y + a2 * z2.y;
    o.z = a0 * z0.z + a1 * z1.z + a2 * z2.z;
    o.w = a0 * z0.w + a1 * z1.w + a2 * z2.w;
    *(float4*)&out[(size_t)n * 128 + d4] = o;
}

// ---------------------------------------------------------------------------
extern "C" void kernel_launch(void* const* d_in, const int* in_sizes, int n_in,
                              void* d_out, int out_size, void* d_ws, size_t ws_size,
                              hipStream_t stream) {
    const float* dstf   = (const float*)d_in[0];
    const float* src0   = (const float*)d_in[1];
    const float* src1   = (const float*)d_in[2];
    const float* src2   = (const float*)d_in[3];
    const float* sem_W1 = (const float*)d_in[4];
    const float* sem_b1 = (const float*)d_in[5];
    const float* sem_W2 = (const float*)d_in[6];
    const float* Wg[3]  = {(const float*)d_in[7],  (const float*)d_in[13], (const float*)d_in[19]};
    const float* al[3]  = {(const float*)d_in[8],  (const float*)d_in[14], (const float*)d_in[20]};
    const float* ar[3]  = {(const float*)d_in[9],  (const float*)d_in[15], (const float*)d_in[21]};
    const float* bg[3]  = {(const float*)d_in[10], (const float*)d_in[16], (const float*)d_in[22]};
    const int*  sidx[3] = {(const int*)d_in[11], (const int*)d_in[17], (const int*)d_in[23]};
    const int*  didx[3] = {(const int*)d_in[12], (const int*)d_in[18], (const int*)d_in[24]};
    float* out = (float*)d_out;

    char* p = (char*)d_ws;
    auto alloc = [&](size_t bytes) -> char* {
        char* q = p; p += (bytes + 255) & ~(size_t)255; return q;
    };
    float*    zm   = (float*)alloc((size_t)N_DST * 3 * 128 * 4);    // 76.8 MB (pairs aliases)
    ushort_t* hs   = (ushort_t*)alloc((size_t)3 * N_SRC * 128 * 2); // 38.4 MB bf16
    float*    elv  = (float*)alloc((size_t)6 * N_DST * 4);
    float*    wv   = (float*)alloc((size_t)6 * 128 * 4);
    float*    wsum = (float*)alloc((size_t)16 * 4);
    float*    aw   = wsum + 8;
    int* cnts       = (int*)alloc((size_t)3 * N_DST * 4);
    int* offs       = (int*)alloc((size_t)3 * N_DST * 4);
    int* perm       = (int*)alloc((size_t)3 * NE * 4);
    int* bucketCnt  = (int*)alloc((size_t)3 * NB * 4);
    int* bucketBase = (int*)alloc((size_t)3 * (NB + 1) * 4);
    int* bucketCur  = (int*)alloc((size_t)3 * NB * 4);
    int2* pairs = (int2*)zm;    // dead before aggregate writes zm

    hipMemsetAsync(bucketCnt, 0, (size_t)3 * NB * 4, stream);
    hipMemsetAsync(wsum, 0, (size_t)16 * 4, stream);

    vec_kernel<<<3, 128, 0, stream>>>(Wg[0], Wg[1], Wg[2], al[0], al[1], al[2],
                                      ar[0], ar[1], ar[2], wv);
    matvec_kernel<<<75000, 256, 0, stream>>>(src0, src1, src2, dstf, wv, elv);

    bucket_hist_kernel<<<3 * NBLK_REL, 256, 0, stream>>>(didx[0], didx[1], didx[2], bucketCnt);
    bucket_scan_kernel<<<3, 256, 0, stream>>>(bucketCnt, bucketBase, bucketCur);
    bucket_scatter_kernel<<<3 * NBLK_REL, 256, 0, stream>>>(didx[0], didx[1], didx[2],
                                                            sidx[0], sidx[1], sidx[2],
                                                            bucketCur, pairs);
    csr_kernel<<<3 * NB, 256, 0, stream>>>(pairs, bucketBase, offs, cnts, perm);

    gemm_kernel<<<3 * GEMM_BLKS, 256, 0, stream>>>(src0, src1, src2,
                                                   Wg[0], Wg[1], Wg[2], hs);
    aggregate_kernel<<<3 * N_DST, 128, 0, stream>>>(hs, elv, perm, offs, cnts,
                                                    bg[0], bg[1], bg[2], zm);
    semantic_kernel<<<(3 * N_DST + 63) / 64, 256, 0, stream>>>(zm, sem_W1, sem_b1, sem_W2, wsum);
    finalize_kernel<<<1, 64, 0, stream>>>(wsum, aw, out + (size_t)N_DST * 128);
    combine_kernel<<<6250, 256, 0, stream>>>(zm, aw, out);
}

// Round 4
// 530.746 us; speedup vs baseline: 1.8691x; 1.2121x over previous
//
#include <hip/hip_runtime.h>
#include <math.h>

#define D_DIM 128
#define N_DST 50000
#define N_SRC 50000
#define NE    800000
#define NEG_SLOPE 0.2f

#define NB          196     // coarse buckets: dst>>8
#define CHUNK       2048
#define NBLK_REL    391     // ceil(NE / CHUNK)
#define GEMM_BLKS   1563    // ceil(N_SRC / 32)

typedef unsigned short ushort_t;
using f32x4  = __attribute__((ext_vector_type(4))) float;
using bf16x8 = __attribute__((ext_vector_type(8))) short;

__device__ __forceinline__ ushort_t f2bf(float x) {
    unsigned u = __float_as_uint(x);
    unsigned r = (u + 0x7fffu + ((u >> 16) & 1u)) >> 16;
    return (ushort_t)r;
}
__device__ __forceinline__ float bf2f(ushort_t b) {
    return __uint_as_float(((unsigned)b) << 16);
}
__device__ __forceinline__ float tanh_fast(float x) {
    float e = __expf(2.f * x);
    return 1.f - 2.f / (e + 1.f);
}

// ---------------------------------------------------------------------------
// wal_r = Wg_r @ al_r,  war_r = Wg_r @ ar_r
__global__ void vec_kernel(const float* __restrict__ Wg0, const float* __restrict__ Wg1,
                           const float* __restrict__ Wg2,
                           const float* __restrict__ al0, const float* __restrict__ al1,
                           const float* __restrict__ al2,
                           const float* __restrict__ ar0, const float* __restrict__ ar1,
                           const float* __restrict__ ar2,
                           float* __restrict__ wv) {
    int r = blockIdx.x;
    const float* W  = r == 0 ? Wg0 : (r == 1 ? Wg1 : Wg2);
    const float* al = r == 0 ? al0 : (r == 1 ? al1 : al2);
    const float* ar = r == 0 ? ar0 : (r == 1 ? ar1 : ar2);
    int i = threadIdx.x;
    float sal = 0.f, sar = 0.f;
    for (int j = 0; j < D_DIM; j++) {
        float w = W[i * D_DIM + j];
        sal = fmaf(w, al[j], sal);
        sar = fmaf(w, ar[j], sar);
    }
    wv[r * D_DIM + i]       = sal;
    wv[(3 + r) * D_DIM + i] = sar;
}

// ---------------------------------------------------------------------------
__global__ void matvec_kernel(const float* __restrict__ src0, const float* __restrict__ src1,
                              const float* __restrict__ src2, const float* __restrict__ dstf,
                              const float* __restrict__ wv, float* __restrict__ elv) {
    int job  = blockIdx.x / 12500;
    int blk  = blockIdx.x % 12500;
    int wave = threadIdx.x >> 6;
    int lane = threadIdx.x & 63;
    int row  = blk * 4 + wave;
    const float* M = job == 0 ? src0 : (job == 1 ? src1 : (job == 2 ? src2 : dstf));
    const float* v = wv + job * D_DIM;
    const float* mr = M + (size_t)row * D_DIM;
    float p = fmaf(mr[lane], v[lane], mr[lane + 64] * v[lane + 64]);
    #pragma unroll
    for (int off = 32; off > 0; off >>= 1) p += __shfl_down(p, off);
    if (lane == 0) elv[job * N_DST + row] = p;
}

// ---------------------------------------------------------------------------
// fused fp32 GEMM, all 3 relations: hs_r[n,:] = bf16( src_r[n,:] @ Wg_r )
__global__ __launch_bounds__(256) void gemm_kernel(
        const float* __restrict__ A0, const float* __restrict__ A1, const float* __restrict__ A2,
        const float* __restrict__ W0, const float* __restrict__ W1, const float* __restrict__ W2,
        ushort_t* __restrict__ hs) {
    __shared__ __align__(16) float As[32][128];
    __shared__ __align__(16) float Ws[32][128];
    int rel = blockIdx.x / GEMM_BLKS, blk = blockIdx.x % GEMM_BLKS;
    const float* A = rel == 0 ? A0 : (rel == 1 ? A1 : A2);
    const float* W = rel == 0 ? W0 : (rel == 1 ? W1 : W2);
    ushort_t* C = hs + (size_t)rel * N_SRC * 128;
    int tid  = threadIdx.x;
    int row0 = blk * 32;
    int colg = tid & 31, rowg = tid >> 5;
    int col4 = colg * 4;

    #pragma unroll
    for (int j = 0; j < 4; j++) {
        int f4 = tid + j * 256;
        int m = f4 >> 5, k4 = (f4 & 31) * 4;
        int gr = row0 + m; if (gr > N_SRC - 1) gr = N_SRC - 1;
        *(float4*)&As[m][k4] = *(const float4*)&A[(size_t)gr * 128 + k4];
    }

    float acc[4][4] = {};
    for (int kb = 0; kb < 4; kb++) {
        #pragma unroll
        for (int j = 0; j < 4; j++) {
            int f4 = tid + j * 256;
            int kk = f4 >> 5, n4 = (f4 & 31) * 4;
            *(float4*)&Ws[kk][n4] = *(const float4*)&W[(size_t)(kb * 32 + kk) * 128 + n4];
        }
        __syncthreads();
        #pragma unroll
        for (int kk = 0; kk < 32; kk += 4) {
            float a_[4][4], w_[4][4];
            #pragma unroll
            for (int r_ = 0; r_ < 4; r_++) {
                float4 t = *(const float4*)&As[rowg * 4 + r_][kb * 32 + kk];
                a_[r_][0] = t.x; a_[r_][1] = t.y; a_[r_][2] = t.z; a_[r_][3] = t.w;
            }
            #pragma unroll
            for (int k_ = 0; k_ < 4; k_++) {
                float4 t = *(const float4*)&Ws[kk + k_][col4];
                w_[k_][0] = t.x; w_[k_][1] = t.y; w_[k_][2] = t.z; w_[k_][3] = t.w;
            }
            #pragma unroll
            for (int k_ = 0; k_ < 4; k_++)
                #pragma unroll
                for (int r_ = 0; r_ < 4; r_++)
                    #pragma unroll
                    for (int c_ = 0; c_ < 4; c_++)
                        acc[r_][c_] = fmaf(a_[r_][k_], w_[k_][c_], acc[r_][c_]);
        }
        __syncthreads();
    }
    #pragma unroll
    for (int r_ = 0; r_ < 4; r_++) {
        int gr = row0 + rowg * 4 + r_;
        if (gr < N_SRC) {
            ushort4 t = make_ushort4(f2bf(acc[r_][0]), f2bf(acc[r_][1]),
                                     f2bf(acc[r_][2]), f2bf(acc[r_][3]));
            *(ushort4*)&C[(size_t)gr * 128 + col4] = t;
        }
    }
}

// ---------------------------------------------------------------------------
// CSR build (two-level counting sort)
__global__ __launch_bounds__(256) void bucket_hist_kernel(
        const int* __restrict__ d0, const int* __restrict__ d1, const int* __restrict__ d2,
        int* __restrict__ bucketCnt) {
    __shared__ int cnt[NB];
    int bx = blockIdx.x;
    int r = bx / NBLK_REL, blk = bx % NBLK_REL;
    const int* dd = r == 0 ? d0 : (r == 1 ? d1 : d2);
    int tid = threadIdx.x;
    if (tid < NB) cnt[tid] = 0;
    __syncthreads();
    int e0 = blk * CHUNK, e1 = min(e0 + CHUNK, NE);
    for (int e = e0 + tid; e < e1; e += 256) atomicAdd(&cnt[dd[e] >> 8], 1);
    __syncthreads();
    if (tid < NB && cnt[tid]) atomicAdd(&bucketCnt[r * NB + tid], cnt[tid]);
}

__global__ __launch_bounds__(256) void bucket_scan_kernel(
        const int* __restrict__ bucketCnt, int* __restrict__ bucketBase,
        int* __restrict__ bucketCur) {
    __shared__ int sc[256];
    int r = blockIdx.x, tid = threadIdx.x;
    int v = tid < NB ? bucketCnt[r * NB + tid] : 0;
    sc[tid] = v;
    __syncthreads();
    for (int off = 1; off < 256; off <<= 1) {
        int t = tid >= off ? sc[tid - off] : 0;
        __syncthreads();
        sc[tid] += t;
        __syncthreads();
    }
    int excl = sc[tid] - v;
    if (tid < NB) { bucketBase[r * (NB + 1) + tid] = excl; bucketCur[r * NB + tid] = excl; }
    if (tid == 255) bucketBase[r * (NB + 1) + NB] = sc[255];
}

__global__ __launch_bounds__(256) void bucket_scatter_kernel(
        const int* __restrict__ d0, const int* __restrict__ d1, const int* __restrict__ d2,
        const int* __restrict__ s0, const int* __restrict__ s1, const int* __restrict__ s2,
        int* __restrict__ bucketCur, int2* __restrict__ pairs) {
    __shared__ int cnt[NB], base[NB], cur[NB];
    int bx = blockIdx.x;
    int r = bx / NBLK_REL, blk = bx % NBLK_REL;
    const int* dd = r == 0 ? d0 : (r == 1 ? d1 : d2);
    const int* ss = r == 0 ? s0 : (r == 1 ? s1 : s2);
    int tid = threadIdx.x;
    if (tid < NB) { cnt[tid] = 0; cur[tid] = 0; }
    __syncthreads();
    int e0 = blk * CHUNK, e1 = min(e0 + CHUNK, NE);
    for (int e = e0 + tid; e < e1; e += 256) atomicAdd(&cnt[dd[e] >> 8], 1);
    __syncthreads();
    if (tid < NB) base[tid] = cnt[tid] ? atomicAdd(&bucketCur[r * NB + tid], cnt[tid]) : 0;
    __syncthreads();
    int2* pr = pairs + (size_t)r * NE;
    for (int e = e0 + tid; e < e1; e += 256) {
        int d = dd[e], b = d >> 8;
        int rank = atomicAdd(&cur[b], 1);
        pr[base[b] + rank] = make_int2(ss[e], d);
    }
}

__global__ __launch_bounds__(256) void csr_kernel(
        const int2* __restrict__ pairs, const int* __restrict__ bucketBase,
        int* __restrict__ offs, int* __restrict__ cnts, int* __restrict__ perm) {
    __shared__ int hist[256], sc[256], cur[256];
    int bx = blockIdx.x;
    int r = bx / NB, b = bx % NB;
    int tid = threadIdx.x;
    int seg0 = bucketBase[r * (NB + 1) + b];
    int seg1 = bucketBase[r * (NB + 1) + b + 1];
    int nE = seg1 - seg0;
    const int2* pr = pairs + (size_t)r * NE + seg0;
    hist[tid] = 0;
    __syncthreads();
    for (int i = tid; i < nE; i += 256) atomicAdd(&hist[pr[i].y & 255], 1);
    __syncthreads();
    int v = hist[tid];
    sc[tid] = v;
    __syncthreads();
    for (int off = 1; off < 256; off <<= 1) {
        int t = tid >= off ? sc[tid - off] : 0;
        __syncthreads();
        sc[tid] += t;
        __syncthreads();
    }
    int excl = sc[tid] - v;
    int dstg = b * 256 + tid;
    if (dstg < N_DST) { offs[r * N_DST + dstg] = seg0 + excl; cnts[r * N_DST + dstg] = v; }
    cur[tid] = excl;
    __syncthreads();
    int* pm = perm + (size_t)r * NE + seg0;
    for (int i = tid; i < nE; i += 256) {
        int2 p = pr[i];
        int rank = atomicAdd(&cur[p.y & 255], 1);
        pm[rank] = p.x;
    }
}

// ---------------------------------------------------------------------------
// edge softmax + aggregation: one WAVE per dst node, 4 waves/block.
// Edge (src, exp-logit) staged once in per-wave LDS slots; gather is ushort4
// (8 B/lane, 32 lanes/row -> 2 edge rows per wave-load, 4 edges in flight).
// 1/Z folded into epilogue. No __syncthreads (wave-local only).
__global__ __launch_bounds__(256) void aggregate_kernel(
        const ushort_t* __restrict__ hs, const float* __restrict__ elv,
        const int* __restrict__ perm, const int* __restrict__ offs,
        const int* __restrict__ cnts,
        const float* __restrict__ bg0, const float* __restrict__ bg1,
        const float* __restrict__ bg2, float* __restrict__ zm) {
    __shared__ int2 ew[4][132];           // per-wave: (src, x-or-exp bits)
    int wave = threadIdx.x >> 6, lane = threadIdx.x & 63;
    int bx  = blockIdx.x;
    int rel = bx / 12500;
    int b   = (bx % 12500) * 4 + wave;    // dst node, always < 50000
    const float* el  = elv + rel * N_DST;
    float erb = elv[(3 + rel) * N_DST + b];
    const float* bg = rel == 0 ? bg0 : (rel == 1 ? bg1 : bg2);
    const int* pm = perm + (size_t)rel * NE;
    const ushort_t* hsr = hs + (size_t)rel * N_SRC * 128;
    int o0 = offs[rel * N_DST + b], deg = cnts[rel * N_DST + b];
    float* zout = zm + ((size_t)b * 3 + rel) * 128;

    if (deg <= 128) {
        int i0 = lane, i1 = lane + 64;
        int s0 = 0, s1 = 0;
        float x0 = -INFINITY, x1 = -INFINITY;
        if (i0 < deg) { s0 = pm[o0 + i0]; float x = el[s0] + erb; x0 = x >= 0.f ? x : NEG_SLOPE * x; }
        if (i1 < deg) { s1 = pm[o0 + i1]; float x = el[s1] + erb; x1 = x >= 0.f ? x : NEG_SLOPE * x; }
        float m = fmaxf(x0, x1);
        #pragma unroll
        for (int msk = 1; msk < 64; msk <<= 1) m = fmaxf(m, __shfl_xor(m, msk));
        float e0 = (i0 < deg) ? __expf(x0 - m) : 0.f;
        float e1 = (i1 < deg) ? __expf(x1 - m) : 0.f;
        float lsum = e0 + e1;
        #pragma unroll
        for (int msk = 1; msk < 64; msk <<= 1) lsum += __shfl_xor(lsum, msk);
        float invz = deg > 0 ? 1.f / lsum : 0.f;

        // stage (src, exp) slots; sanitize pad slots 128..131
        ew[wave][i0] = make_int2(s0, __float_as_int(e0));
        ew[wave][i1] = make_int2(s1, __float_as_int(e1));
        if (lane < 4) ew[wave][128 + lane] = make_int2(0, 0);
        __asm__ __volatile__("" ::: "memory");   // in-wave LDS is FIFO-ordered

        float a0 = 0.f, a1 = 0.f, a2 = 0.f, a3 = 0.f;
        int half = lane >> 5, col = (lane & 31) * 4;
        for (int j = 0; j < deg; j += 4) {
            int ja = j + half, jb = j + 2 + half;
            int2 pA = ew[wave][ja];
            int2 pB = ew[wave][jb];
            float eA = (ja < deg) ? __int_as_float(pA.y) : 0.f;
            float eB = (jb < deg) ? __int_as_float(pB.y) : 0.f;
            const uint2 hA = *(const uint2*)(hsr + (size_t)pA.x * 128 + col);
            const uint2 hB = *(const uint2*)(hsr + (size_t)pB.x * 128 + col);
            a0 = fmaf(eA, __uint_as_float(hA.x << 16),          a0);
            a1 = fmaf(eA, __uint_as_float(hA.x & 0xffff0000u),  a1);
            a2 = fmaf(eA, __uint_as_float(hA.y << 16),          a2);
            a3 = fmaf(eA, __uint_as_float(hA.y & 0xffff0000u),  a3);
            a0 = fmaf(eB, __uint_as_float(hB.x << 16),          a0);
            a1 = fmaf(eB, __uint_as_float(hB.x & 0xffff0000u),  a1);
            a2 = fmaf(eB, __uint_as_float(hB.y << 16),          a2);
            a3 = fmaf(eB, __uint_as_float(hB.y & 0xffff0000u),  a3);
        }
        a0 += __shfl_xor(a0, 32);
        a1 += __shfl_xor(a1, 32);
        a2 += __shfl_xor(a2, 32);
        a3 += __shfl_xor(a3, 32);
        if (half == 0) {
            float4 bgv = *(const float4*)&bg[col];
            float4 z;
            z.x = fmaf(a0, invz, bgv.x);
            z.y = fmaf(a1, invz, bgv.y);
            z.z = fmaf(a2, invz, bgv.z);
            z.w = fmaf(a3, invz, bgv.w);
            z.x = z.x > 0.f ? z.x : expm1f(z.x);
            z.y = z.y > 0.f ? z.y : expm1f(z.y);
            z.z = z.z > 0.f ? z.z : expm1f(z.z);
            z.w = z.w > 0.f ? z.w : expm1f(z.w);
            *(float4*)&zout[col] = z;
        }
    } else {
        // slow path (deg > 128): never hit for Poisson(16) degrees, kept for correctness
        float lmax = -INFINITY;
        for (int i = lane; i < deg; i += 64) {
            int s = pm[o0 + i];
            float x = el[s] + erb;
            x = x >= 0.f ? x : NEG_SLOPE * x;
            lmax = fmaxf(lmax, x);
        }
        #pragma unroll
        for (int msk = 1; msk < 64; msk <<= 1) lmax = fmaxf(lmax, __shfl_xor(lmax, msk));
        float lsum = 0.f;
        for (int i = lane; i < deg; i += 64) {
            int s = pm[o0 + i];
            float x = el[s] + erb;
            x = x >= 0.f ? x : NEG_SLOPE * x;
            lsum += __expf(x - lmax);
        }
        #pragma unroll
        for (int msk = 1; msk < 64; msk <<= 1) lsum += __shfl_xor(lsum, msk);
        float invz = 1.f / lsum;
        float c0 = 0.f, c1 = 0.f;
        int col2 = lane * 2;
        for (int j = 0; j < deg; j++) {
            int s = pm[o0 + j];
            float x = el[s] + erb;
            x = x >= 0.f ? x : NEG_SLOPE * x;
            float e_ = __expf(x - lmax);
            unsigned hv = *(const unsigned*)(hsr + (size_t)s * 128 + col2);
            c0 = fmaf(e_, __uint_as_float(hv << 16),         c0);
            c1 = fmaf(e_, __uint_as_float(hv & 0xffff0000u), c1);
        }
        float2 z;
        z.x = fmaf(c0, invz, bg[col2]);
        z.y = fmaf(c1, invz, bg[col2 + 1]);
        z.x = z.x > 0.f ? z.x : expm1f(z.x);
        z.y = z.y > 0.f ? z.y : expm1f(z.y);
        *(float2*)&zout[col2] = z;
    }
}

// ---------------------------------------------------------------------------
// semantic attention via bf16 MFMA: w_sum[r] += sum_n tanh(zm[n,r,:]@W1+b1)@W2
__global__ __launch_bounds__(256) void semantic_kernel(
        const float* __restrict__ zm, const float* __restrict__ W1,
        const float* __restrict__ b1, const float* __restrict__ W2,
        float* __restrict__ w_sum) {
    __shared__ ushort_t Wt[128 * 136];   // Wt[n][k] = bf16(W1[k][n]), stride 136
    __shared__ float hsum[3];
    const int NROWS = N_DST * 3;
    int tid = threadIdx.x;
    if (tid < 3) hsum[tid] = 0.f;

    #pragma unroll
    for (int i = 0; i < 16; i++) {
        int p = i * 256 + tid;
        int n = p & 127, kq = p >> 7;
        int k = kq * 4;
        ushort4 t = make_ushort4(f2bf(W1[(size_t)(k + 0) * 128 + n]),
                                 f2bf(W1[(size_t)(k + 1) * 128 + n]),
                                 f2bf(W1[(size_t)(k + 2) * 128 + n]),
                                 f2bf(W1[(size_t)(k + 3) * 128 + n]));
        *(ushort4*)&Wt[n * 136 + k] = t;
    }
    __syncthreads();

    int w    = tid >> 6, lane = tid & 63;
    int quad = lane >> 4, l15 = lane & 15;
    long row0 = (long)blockIdx.x * 64 + w * 16;
    long rA = row0 + l15; if (rA > NROWS - 1) rA = NROWS - 1;

    f32x4 acc[8] = {};
    #pragma unroll
    for (int kc = 0; kc < 4; kc++) {
        int k0 = kc * 32 + quad * 8;
        const float* src = zm + (size_t)rA * 128 + k0;
        float4 f0 = *(const float4*)src;
        float4 f1 = *(const float4*)(src + 4);
        bf16x8 a;
        a[0] = (short)f2bf(f0.x); a[1] = (short)f2bf(f0.y);
        a[2] = (short)f2bf(f0.z); a[3] = (short)f2bf(f0.w);
        a[4] = (short)f2bf(f1.x); a[5] = (short)f2bf(f1.y);
        a[6] = (short)f2bf(f1.z); a[7] = (short)f2bf(f1.w);
        #pragma unroll
        for (int nt = 0; nt < 8; nt++) {
            int n = nt * 16 + l15;
            bf16x8 bfr = *(const bf16x8*)&Wt[n * 136 + k0];
            acc[nt] = __builtin_amdgcn_mfma_f32_16x16x32_bf16(a, bfr, acc[nt], 0, 0, 0);
        }
    }

    float part[4] = {0.f, 0.f, 0.f, 0.f};
    #pragma unroll
    for (int nt = 0; nt < 8; nt++) {
        int n = nt * 16 + l15;
        float bb = b1[n], ww = W2[n];
        #pragma unroll
        for (int i = 0; i < 4; i++) {
            float t = tanh_fast(acc[nt][i] + bb);
            part[i] = fmaf(t, ww, part[i]);
        }
    }
    #pragma unroll
    for (int msk = 1; msk < 16; msk <<= 1)
        #pragma unroll
        for (int i = 0; i < 4; i++) part[i] += __shfl_xor(part[i], msk);
    if (l15 == 0) {
        #pragma unroll
        for (int i = 0; i < 4; i++) {
            long R = row0 + quad * 4 + i;
            if (R < NROWS) atomicAdd(&hsum[(int)(R % 3)], part[i]);
        }
    }
    __syncthreads();
    if (tid < 3) atomicAdd(&w_sum[tid], hsum[tid]);
}

// ---------------------------------------------------------------------------
__global__ void finalize_kernel(const float* __restrict__ w_sum, float* __restrict__ aw,
                                float* __restrict__ out_att) {
    if (threadIdx.x == 0 && blockIdx.x == 0) {
        float w0 = w_sum[0] / (float)N_DST;
        float w1 = w_sum[1] / (float)N_DST;
        float w2 = w_sum[2] / (float)N_DST;
        float m = fmaxf(w0, fmaxf(w1, w2));
        float e0 = expf(w0 - m), e1 = expf(w1 - m), e2 = expf(w2 - m);
        float s = e0 + e1 + e2;
        aw[0] = e0 / s; aw[1] = e1 / s; aw[2] = e2 / s;
        out_att[0] = aw[0]; out_att[1] = aw[1]; out_att[2] = aw[2];
    }
}

__global__ void combine_kernel(const float* __restrict__ zm, const float* __restrict__ aw,
                               float* __restrict__ out) {
    int id4 = blockIdx.x * 256 + threadIdx.x;
    float a0 = aw[0], a1 = aw[1], a2 = aw[2];
    int n  = id4 >> 5;
    int d4 = (id4 & 31) * 4;
    const float4 z0 = *(const float4*)&zm[((size_t)n * 3 + 0) * 128 + d4];
    const float4 z1 = *(const float4*)&zm[((size_t)n * 3 + 1) * 128 + d4];
    const float4 z2 = *(const float4*)&zm[((size_t)n * 3 + 2) * 128 + d4];
    float4 o;
    o.x = a0 * z0.x + a1 * z1.x + a2 * z2.x;
    o.y = a0 * z0.y + a1 * z1.y + a2 * z2.y;
    o.z = a0 * z0.z + a1 * z1.z + a2 * z2.z;
    o.w = a0 * z0.w + a1 * z1.w + a2 * z2.w;
    *(float4*)&out[(size_t)n * 128 + d4] = o;
}

// ---------------------------------------------------------------------------
extern "C" void kernel_launch(void* const* d_in, const int* in_sizes, int n_in,
                              void* d_out, int out_size, void* d_ws, size_t ws_size,
                              hipStream_t stream) {
    const float* dstf   = (const float*)d_in[0];
    const float* src0   = (const float*)d_in[1];
    const float* src1   = (const float*)d_in[2];
    const float* src2   = (const float*)d_in[3];
    const float* sem_W1 = (const float*)d_in[4];
    const float* sem_b1 = (const float*)d_in[5];
    const float* sem_W2 = (const float*)d_in[6];
    const float* Wg[3]  = {(const float*)d_in[7],  (const float*)d_in[13], (const float*)d_in[19]};
    const float* al[3]  = {(const float*)d_in[8],  (const float*)d_in[14], (const float*)d_in[20]};
    const float* ar[3]  = {(const float*)d_in[9],  (const float*)d_in[15], (const float*)d_in[21]};
    const float* bg[3]  = {(const float*)d_in[10], (const float*)d_in[16], (const float*)d_in[22]};
    const int*  sidx[3] = {(const int*)d_in[11], (const int*)d_in[17], (const int*)d_in[23]};
    const int*  didx[3] = {(const int*)d_in[12], (const int*)d_in[18], (const int*)d_in[24]};
    float* out = (float*)d_out;

    char* p = (char*)d_ws;
    auto alloc = [&](size_t bytes) -> char* {
        char* q = p; p += (bytes + 255) & ~(size_t)255; return q;
    };
    float*    zm   = (float*)alloc((size_t)N_DST * 3 * 128 * 4);    // 76.8 MB (pairs aliases)
    ushort_t* hs   = (ushort_t*)alloc((size_t)3 * N_SRC * 128 * 2); // 38.4 MB bf16
    float*    elv  = (float*)alloc((size_t)6 * N_DST * 4);
    float*    wv   = (float*)alloc((size_t)6 * 128 * 4);
    float*    wsum = (float*)alloc((size_t)16 * 4);
    float*    aw   = wsum + 8;
    int* cnts       = (int*)alloc((size_t)3 * N_DST * 4);
    int* offs       = (int*)alloc((size_t)3 * N_DST * 4);
    int* perm       = (int*)alloc((size_t)3 * NE * 4);
    int* bucketCnt  = (int*)alloc((size_t)3 * NB * 4);
    int* bucketBase = (int*)alloc((size_t)3 * (NB + 1) * 4);
    int* bucketCur  = (int*)alloc((size_t)3 * NB * 4);
    int2* pairs = (int2*)zm;    // dead before aggregate writes zm

    hipMemsetAsync(bucketCnt, 0, (size_t)3 * NB * 4, stream);
    hipMemsetAsync(wsum, 0, (size_t)16 * 4, stream);

    vec_kernel<<<3, 128, 0, stream>>>(Wg[0], Wg[1], Wg[2], al[0], al[1], al[2],
                                      ar[0], ar[1], ar[2], wv);
    matvec_kernel<<<75000, 256, 0, stream>>>(src0, src1, src2, dstf, wv, elv);

    bucket_hist_kernel<<<3 * NBLK_REL, 256, 0, stream>>>(didx[0], didx[1], didx[2], bucketCnt);
    bucket_scan_kernel<<<3, 256, 0, stream>>>(bucketCnt, bucketBase, bucketCur);
    bucket_scatter_kernel<<<3 * NBLK_REL, 256, 0, stream>>>(didx[0], didx[1], didx[2],
                                                            sidx[0], sidx[1], sidx[2],
                                                            bucketCur, pairs);
    csr_kernel<<<3 * NB, 256, 0, stream>>>(pairs, bucketBase, offs, cnts, perm);

    gemm_kernel<<<3 * GEMM_BLKS, 256, 0, stream>>>(src0, src1, src2,
                                                   Wg[0], Wg[1], Wg[2], hs);
    aggregate_kernel<<<3 * 12500, 256, 0, stream>>>(hs, elv, perm, offs, cnts,
                                                    bg[0], bg[1], bg[2], zm);
    semantic_kernel<<<(3 * N_DST + 63) / 64, 256, 0, stream>>>(zm, sem_W1, sem_b1, sem_W2, wsum);
    finalize_kernel<<<1, 64, 0, stream>>>(wsum, aw, out + (size_t)N_DST * 128);
    combine_kernel<<<6250, 256, 0, stream>>>(zm, aw, out);
}

// Round 5
// 498.403 us; speedup vs baseline: 1.9904x; 1.0649x over previous
//
#include <hip/hip_runtime.h>
#include <math.h>

#define D_DIM 128
#define N_DST 50000
#define N_SRC 50000
#define NE    800000
#define NEG_SLOPE 0.2f

#define NB          196     // coarse buckets: dst>>8
#define CHUNK       8192    // edges per block in bucket passes
#define NBLK_REL    98      // ceil(NE / CHUNK)
#define GEMM_BLKS   1563    // ceil(N_SRC / 32)

typedef unsigned short ushort_t;
using f32x4  = __attribute__((ext_vector_type(4))) float;
using bf16x8 = __attribute__((ext_vector_type(8))) short;

__device__ __forceinline__ ushort_t f2bf(float x) {
    unsigned u = __float_as_uint(x);
    unsigned r = (u + 0x7fffu + ((u >> 16) & 1u)) >> 16;
    return (ushort_t)r;
}
__device__ __forceinline__ float bflo(unsigned u) { return __uint_as_float(u << 16); }
__device__ __forceinline__ float bfhi(unsigned u) { return __uint_as_float(u & 0xffff0000u); }
__device__ __forceinline__ float tanh_fast(float x) {
    float e = __expf(2.f * x);
    return 1.f - 2.f / (e + 1.f);
}

// ---------------------------------------------------------------------------
// war_r = Wg_r @ ar_r  (only er needs a matvec now; el fused into gemm)
__global__ void vec_kernel(const float* __restrict__ Wg0, const float* __restrict__ Wg1,
                           const float* __restrict__ Wg2,
                           const float* __restrict__ ar0, const float* __restrict__ ar1,
                           const float* __restrict__ ar2,
                           float* __restrict__ wv) {
    int r = blockIdx.x;
    const float* W  = r == 0 ? Wg0 : (r == 1 ? Wg1 : Wg2);
    const float* ar = r == 0 ? ar0 : (r == 1 ? ar1 : ar2);
    int i = threadIdx.x;
    float sar = 0.f;
    for (int j = 0; j < D_DIM; j++) sar = fmaf(W[i * D_DIM + j], ar[j], sar);
    wv[r * D_DIM + i] = sar;
}

// ---------------------------------------------------------------------------
// er_r[n] = dot(dstf[n,:], war_r) for r=0..2 — one pass over dstf
__global__ void er_kernel(const float* __restrict__ dstf, const float* __restrict__ wv,
                          float* __restrict__ elv) {
    int wave = threadIdx.x >> 6, lane = threadIdx.x & 63;
    int row  = blockIdx.x * 4 + wave;
    const float* mr = dstf + (size_t)row * D_DIM;
    float m0 = mr[lane], m1 = mr[lane + 64];
    #pragma unroll
    for (int r = 0; r < 3; r++) {
        float p = fmaf(m0, wv[r * 128 + lane], m1 * wv[r * 128 + lane + 64]);
        #pragma unroll
        for (int off = 32; off > 0; off >>= 1) p += __shfl_down(p, off);
        if (lane == 0) elv[(3 + r) * N_DST + row] = p;
    }
}

// ---------------------------------------------------------------------------
// prep: Wt_g[n*128+k] = bf16(W1[k*128+n])  (once, tiny)
__global__ void prep_w1_kernel(const float* __restrict__ W1, ushort_t* __restrict__ Wt_g) {
    int idx = blockIdx.x * 256 + threadIdx.x;     // 16384
    int k = idx >> 7, n = idx & 127;
    Wt_g[n * 128 + k] = f2bf(W1[idx]);
}

// ---------------------------------------------------------------------------
// fused fp32 GEMM, all 3 relations: hs_r = bf16(src_r @ Wg_r); el_r fused in epilogue
__global__ __launch_bounds__(256) void gemm_kernel(
        const float* __restrict__ A0, const float* __restrict__ A1, const float* __restrict__ A2,
        const float* __restrict__ W0, const float* __restrict__ W1, const float* __restrict__ W2,
        const float* __restrict__ al0, const float* __restrict__ al1, const float* __restrict__ al2,
        ushort_t* __restrict__ hs, float* __restrict__ elv) {
    __shared__ __align__(16) float As[32][128];
    __shared__ __align__(16) float Ws[32][128];
    int rel = blockIdx.x / GEMM_BLKS, blk = blockIdx.x % GEMM_BLKS;
    const float* A  = rel == 0 ? A0 : (rel == 1 ? A1 : A2);
    const float* W  = rel == 0 ? W0 : (rel == 1 ? W1 : W2);
    const float* al = rel == 0 ? al0 : (rel == 1 ? al1 : al2);
    ushort_t* C = hs + (size_t)rel * N_SRC * 128;
    int tid  = threadIdx.x;
    int row0 = blk * 32;
    int colg = tid & 31, rowg = tid >> 5;
    int col4 = colg * 4;

    #pragma unroll
    for (int j = 0; j < 4; j++) {
        int f4 = tid + j * 256;
        int m = f4 >> 5, k4 = (f4 & 31) * 4;
        int gr = row0 + m; if (gr > N_SRC - 1) gr = N_SRC - 1;
        *(float4*)&As[m][k4] = *(const float4*)&A[(size_t)gr * 128 + k4];
    }

    float acc[4][4] = {};
    for (int kb = 0; kb < 4; kb++) {
        #pragma unroll
        for (int j = 0; j < 4; j++) {
            int f4 = tid + j * 256;
            int kk = f4 >> 5, n4 = (f4 & 31) * 4;
            *(float4*)&Ws[kk][n4] = *(const float4*)&W[(size_t)(kb * 32 + kk) * 128 + n4];
        }
        __syncthreads();
        #pragma unroll
        for (int kk = 0; kk < 32; kk += 4) {
            float a_[4][4], w_[4][4];
            #pragma unroll
            for (int r_ = 0; r_ < 4; r_++) {
                float4 t = *(const float4*)&As[rowg * 4 + r_][kb * 32 + kk];
                a_[r_][0] = t.x; a_[r_][1] = t.y; a_[r_][2] = t.z; a_[r_][3] = t.w;
            }
            #pragma unroll
            for (int k_ = 0; k_ < 4; k_++) {
                float4 t = *(const float4*)&Ws[kk + k_][col4];
                w_[k_][0] = t.x; w_[k_][1] = t.y; w_[k_][2] = t.z; w_[k_][3] = t.w;
            }
            #pragma unroll
            for (int k_ = 0; k_ < 4; k_++)
                #pragma unroll
                for (int r_ = 0; r_ < 4; r_++)
                    #pragma unroll
                    for (int c_ = 0; c_ < 4; c_++)
                        acc[r_][c_] = fmaf(a_[r_][k_], w_[k_][c_], acc[r_][c_]);
        }
        __syncthreads();
    }
    #pragma unroll
    for (int r_ = 0; r_ < 4; r_++) {
        int gr = row0 + rowg * 4 + r_;
        if (gr < N_SRC) {
            ushort4 t = make_ushort4(f2bf(acc[r_][0]), f2bf(acc[r_][1]),
                                     f2bf(acc[r_][2]), f2bf(acc[r_][3]));
            *(ushort4*)&C[(size_t)gr * 128 + col4] = t;
        }
    }
    // el epilogue: el[row] = acc_row @ al, reduced over the 32 col-threads
    float4 al4 = *(const float4*)&al[col4];
    float elp[4];
    #pragma unroll
    for (int r_ = 0; r_ < 4; r_++) {
        float s = fmaf(acc[r_][0], al4.x, acc[r_][1] * al4.y);
        s = fmaf(acc[r_][2], al4.z, s);
        s = fmaf(acc[r_][3], al4.w, s);
        elp[r_] = s;
    }
    #pragma unroll
    for (int msk = 1; msk < 32; msk <<= 1)
        #pragma unroll
        for (int r_ = 0; r_ < 4; r_++) elp[r_] += __shfl_xor(elp[r_], msk);
    if (colg == 0) {
        #pragma unroll
        for (int r_ = 0; r_ < 4; r_++) {
            int gr = row0 + rowg * 4 + r_;
            if (gr < N_SRC) elv[rel * N_DST + gr] = elp[r_];
        }
    }
}

// ---------------------------------------------------------------------------
// CSR build (two-level counting sort)
__global__ __launch_bounds__(256) void bucket_hist_kernel(
        const int* __restrict__ d0, const int* __restrict__ d1, const int* __restrict__ d2,
        int* __restrict__ bucketCnt) {
    __shared__ int cnt[NB];
    int bx = blockIdx.x;
    int r = bx / NBLK_REL, blk = bx % NBLK_REL;
    const int* dd = r == 0 ? d0 : (r == 1 ? d1 : d2);
    int tid = threadIdx.x;
    if (tid < NB) cnt[tid] = 0;
    __syncthreads();
    int e0 = blk * CHUNK, e1 = min(e0 + CHUNK, NE);
    for (int e = e0 + tid; e < e1; e += 256) atomicAdd(&cnt[dd[e] >> 8], 1);
    __syncthreads();
    if (tid < NB && cnt[tid]) atomicAdd(&bucketCnt[r * NB + tid], cnt[tid]);
}

__global__ __launch_bounds__(256) void bucket_scan_kernel(
        const int* __restrict__ bucketCnt, int* __restrict__ bucketBase,
        int* __restrict__ bucketCur) {
    __shared__ int sc[256];
    int r = blockIdx.x, tid = threadIdx.x;
    int v = tid < NB ? bucketCnt[r * NB + tid] : 0;
    sc[tid] = v;
    __syncthreads();
    for (int off = 1; off < 256; off <<= 1) {
        int t = tid >= off ? sc[tid - off] : 0;
        __syncthreads();
        sc[tid] += t;
        __syncthreads();
    }
    int excl = sc[tid] - v;
    if (tid < NB) { bucketBase[r * (NB + 1) + tid] = excl; bucketCur[r * NB + tid] = excl; }
    if (tid == 255) bucketBase[r * (NB + 1) + NB] = sc[255];
}

__global__ __launch_bounds__(256) void bucket_scatter_kernel(
        const int* __restrict__ d0, const int* __restrict__ d1, const int* __restrict__ d2,
        const int* __restrict__ s0, const int* __restrict__ s1, const int* __restrict__ s2,
        int* __restrict__ bucketCur, int2* __restrict__ pairs) {
    __shared__ int cnt[NB], base[NB], cur[NB];
    int bx = blockIdx.x;
    int r = bx / NBLK_REL, blk = bx % NBLK_REL;
    const int* dd = r == 0 ? d0 : (r == 1 ? d1 : d2);
    const int* ss = r == 0 ? s0 : (r == 1 ? s1 : s2);
    int tid = threadIdx.x;
    if (tid < NB) { cnt[tid] = 0; cur[tid] = 0; }
    __syncthreads();
    int e0 = blk * CHUNK, e1 = min(e0 + CHUNK, NE);
    for (int e = e0 + tid; e < e1; e += 256) atomicAdd(&cnt[dd[e] >> 8], 1);
    __syncthreads();
    if (tid < NB) base[tid] = cnt[tid] ? atomicAdd(&bucketCur[r * NB + tid], cnt[tid]) : 0;
    __syncthreads();
    int2* pr = pairs + (size_t)r * NE;
    for (int e = e0 + tid; e < e1; e += 256) {
        int d = dd[e], b = d >> 8;
        int rank = atomicAdd(&cur[b], 1);
        pr[base[b] + rank] = make_int2(ss[e], d);
    }
}

__global__ __launch_bounds__(256) void csr_kernel(
        const int2* __restrict__ pairs, const int* __restrict__ bucketBase,
        int* __restrict__ offs, int* __restrict__ cnts, int* __restrict__ perm) {
    __shared__ int hist[256], sc[256], cur[256];
    int bx = blockIdx.x;
    int r = bx / NB, b = bx % NB;
    int tid = threadIdx.x;
    int seg0 = bucketBase[r * (NB + 1) + b];
    int seg1 = bucketBase[r * (NB + 1) + b + 1];
    int nE = seg1 - seg0;
    const int2* pr = pairs + (size_t)r * NE + seg0;
    hist[tid] = 0;
    __syncthreads();
    for (int i = tid; i < nE; i += 256) atomicAdd(&hist[pr[i].y & 255], 1);
    __syncthreads();
    int v = hist[tid];
    sc[tid] = v;
    __syncthreads();
    for (int off = 1; off < 256; off <<= 1) {
        int t = tid >= off ? sc[tid - off] : 0;
        __syncthreads();
        sc[tid] += t;
        __syncthreads();
    }
    int excl = sc[tid] - v;
    int dstg = b * 256 + tid;
    if (dstg < N_DST) { offs[r * N_DST + dstg] = seg0 + excl; cnts[r * N_DST + dstg] = v; }
    cur[tid] = excl;
    __syncthreads();
    int* pm = perm + (size_t)r * NE + seg0;
    for (int i = tid; i < nE; i += 256) {
        int2 p = pr[i];
        int rank = atomicAdd(&cur[p.y & 255], 1);
        pm[rank] = p.x;
    }
}

// ---------------------------------------------------------------------------
// edge softmax + aggregation: one WAVE per dst, 4 waves/block.
// LDS slots hold (srcByteOffset, alpha) — alpha = exp(x-m)/Z pre-normalized.
// All 128 slots always initialized (alpha=0 past deg) -> guard-free inner
// loop over deg padded to 8. Gather: saddr-form dwordx2, 1 v_add per load.
__global__ __launch_bounds__(256) void aggregate_kernel(
        const ushort_t* __restrict__ hs, const float* __restrict__ elv,
        const int* __restrict__ perm, const int* __restrict__ offs,
        const int* __restrict__ cnts,
        const float* __restrict__ bg0, const float* __restrict__ bg1,
        const float* __restrict__ bg2, float* __restrict__ zm) {
    __shared__ int2 ew[4][128];
    int wave = threadIdx.x >> 6, lane = threadIdx.x & 63;
    int bx  = blockIdx.x;
    int rel = bx / 12500;
    int b   = (bx % 12500) * 4 + wave;
    const float* el  = elv + rel * N_DST;
    float erb = elv[(3 + rel) * N_DST + b];
    const float* bg = rel == 0 ? bg0 : (rel == 1 ? bg1 : bg2);
    const int* pm = perm + (size_t)rel * NE;
    const ushort_t* hsr = hs + (size_t)rel * N_SRC * 128;
    int o0 = offs[rel * N_DST + b], deg = cnts[rel * N_DST + b];
    float* zout = zm + ((size_t)b * 3 + rel) * 128;

    if (deg <= 128) {
        int i0 = lane, i1 = lane + 64;
        int s0 = 0, s1 = 0;
        float x0 = -INFINITY, x1 = -INFINITY;
        if (i0 < deg) { s0 = pm[o0 + i0]; float x = el[s0] + erb; x0 = x >= 0.f ? x : NEG_SLOPE * x; }
        if (i1 < deg) { s1 = pm[o0 + i1]; float x = el[s1] + erb; x1 = x >= 0.f ? x : NEG_SLOPE * x; }
        float m = fmaxf(x0, x1);
        #pragma unroll
        for (int msk = 1; msk < 64; msk <<= 1) m = fmaxf(m, __shfl_xor(m, msk));
        float e0 = (i0 < deg) ? __expf(x0 - m) : 0.f;
        float e1 = (i1 < deg) ? __expf(x1 - m) : 0.f;
        float lsum = e0 + e1;
        #pragma unroll
        for (int msk = 1; msk < 64; msk <<= 1) lsum += __shfl_xor(lsum, msk);
        float invz = deg > 0 ? 1.f / lsum : 0.f;

        ew[wave][i0] = make_int2(s0 * 256, __float_as_int(e0 * invz));
        ew[wave][i1] = make_int2(s1 * 256, __float_as_int(e1 * invz));
        __asm__ __volatile__("" ::: "memory");   // in-wave LDS: compiler fence only

        int degp = (deg + 7) & ~7;
        const char* base = (const char*)hsr;
        int half = lane >> 5;
        int col8 = (lane & 31) * 8;              // byte offset: 4 bf16 per lane
        float2 a01 = {0.f, 0.f}, a23 = {0.f, 0.f};
        for (int j = 0; j < degp; j += 8) {
            int2 pA = ew[wave][j + half];
            int2 pB = ew[wave][j + 2 + half];
            int2 pC = ew[wave][j + 4 + half];
            int2 pD = ew[wave][j + 6 + half];
            uint2 hA = *(const uint2*)(base + (unsigned)(pA.x + col8));
            uint2 hB = *(const uint2*)(base + (unsigned)(pB.x + col8));
            uint2 hC = *(const uint2*)(base + (unsigned)(pC.x + col8));
            uint2 hD = *(const uint2*)(base + (unsigned)(pD.x + col8));
            float eA = __int_as_float(pA.y), eB = __int_as_float(pB.y);
            float eC = __int_as_float(pC.y), eD = __int_as_float(pD.y);
            a01.x = fmaf(eA, bflo(hA.x), a01.x); a01.y = fmaf(eA, bfhi(hA.x), a01.y);
            a23.x = fmaf(eA, bflo(hA.y), a23.x); a23.y = fmaf(eA, bfhi(hA.y), a23.y);
            a01.x = fmaf(eB, bflo(hB.x), a01.x); a01.y = fmaf(eB, bfhi(hB.x), a01.y);
            a23.x = fmaf(eB, bflo(hB.y), a23.x); a23.y = fmaf(eB, bfhi(hB.y), a23.y);
            a01.x = fmaf(eC, bflo(hC.x), a01.x); a01.y = fmaf(eC, bfhi(hC.x), a01.y);
            a23.x = fmaf(eC, bflo(hC.y), a23.x); a23.y = fmaf(eC, bfhi(hC.y), a23.y);
            a01.x = fmaf(eD, bflo(hD.x), a01.x); a01.y = fmaf(eD, bfhi(hD.x), a01.y);
            a23.x = fmaf(eD, bflo(hD.y), a23.x); a23.y = fmaf(eD, bfhi(hD.y), a23.y);
        }
        a01.x += __shfl_xor(a01.x, 32);
        a01.y += __shfl_xor(a01.y, 32);
        a23.x += __shfl_xor(a23.x, 32);
        a23.y += __shfl_xor(a23.y, 32);
        if (half == 0) {
            int col4 = (lane & 31) * 4;
            float4 bgv = *(const float4*)&bg[col4];
            float4 z;
            z.x = a01.x + bgv.x;
            z.y = a01.y + bgv.y;
            z.z = a23.x + bgv.z;
            z.w = a23.y + bgv.w;
            z.x = z.x > 0.f ? z.x : expm1f(z.x);
            z.y = z.y > 0.f ? z.y : expm1f(z.y);
            z.z = z.z > 0.f ? z.z : expm1f(z.z);
            z.w = z.w > 0.f ? z.w : expm1f(z.w);
            *(float4*)&zout[col4] = z;
        }
    } else {
        // slow path (deg > 128): never hit for Poisson(16), kept for correctness
        float lmax = -INFINITY;
        for (int i = lane; i < deg; i += 64) {
            int s = pm[o0 + i];
            float x = el[s] + erb;
            x = x >= 0.f ? x : NEG_SLOPE * x;
            lmax = fmaxf(lmax, x);
        }
        #pragma unroll
        for (int msk = 1; msk < 64; msk <<= 1) lmax = fmaxf(lmax, __shfl_xor(lmax, msk));
        float lsum = 0.f;
        for (int i = lane; i < deg; i += 64) {
            int s = pm[o0 + i];
            float x = el[s] + erb;
            x = x >= 0.f ? x : NEG_SLOPE * x;
            lsum += __expf(x - lmax);
        }
        #pragma unroll
        for (int msk = 1; msk < 64; msk <<= 1) lsum += __shfl_xor(lsum, msk);
        float invz = 1.f / lsum;
        float c0 = 0.f, c1 = 0.f;
        int col2 = lane * 2;
        for (int j = 0; j < deg; j++) {
            int s = pm[o0 + j];
            float x = el[s] + erb;
            x = x >= 0.f ? x : NEG_SLOPE * x;
            float e_ = __expf(x - lmax) * invz;
            unsigned hv = *(const unsigned*)(hsr + (size_t)s * 128 + col2);
            c0 = fmaf(e_, bflo(hv), c0);
            c1 = fmaf(e_, bfhi(hv), c1);
        }
        float2 z;
        z.x = c0 + bg[col2];
        z.y = c1 + bg[col2 + 1];
        z.x = z.x > 0.f ? z.x : expm1f(z.x);
        z.y = z.y > 0.f ? z.y : expm1f(z.y);
        *(float2*)&zout[col2] = z;
    }
}

// ---------------------------------------------------------------------------
// semantic attention via bf16 MFMA; W1^T pre-converted to bf16 in Wt_g
__global__ __launch_bounds__(256) void semantic_kernel(
        const float* __restrict__ zm, const ushort_t* __restrict__ Wt_g,
        const float* __restrict__ b1, const float* __restrict__ W2,
        float* __restrict__ w_sum) {
    __shared__ ushort_t Wt[128 * 136];   // Wt[n][k], stride 136
    __shared__ float hsum[3];
    const int NROWS = N_DST * 3;
    int tid = threadIdx.x;
    if (tid < 3) hsum[tid] = 0.f;

    #pragma unroll
    for (int i = 0; i < 8; i++) {
        int c = i * 256 + tid;          // 2048 chunks of 8 ushorts
        int n = c >> 4, c16 = c & 15;
        uint4 t = *(const uint4*)(Wt_g + n * 128 + c16 * 8);
        *(uint4*)&Wt[n * 136 + c16 * 8] = t;
    }
    __syncthreads();

    int w    = tid >> 6, lane = tid & 63;
    int quad = lane >> 4, l15 = lane & 15;
    long row0 = (long)blockIdx.x * 64 + w * 16;
    long rA = row0 + l15; if (rA > NROWS - 1) rA = NROWS - 1;

    f32x4 acc[8] = {};
    #pragma unroll
    for (int kc = 0; kc < 4; kc++) {
        int k0 = kc * 32 + quad * 8;
        const float* src = zm + (size_t)rA * 128 + k0;
        float4 f0 = *(const float4*)src;
        float4 f1 = *(const float4*)(src + 4);
        bf16x8 a;
        a[0] = (short)f2bf(f0.x); a[1] = (short)f2bf(f0.y);
        a[2] = (short)f2bf(f0.z); a[3] = (short)f2bf(f0.w);
        a[4] = (short)f2bf(f1.x); a[5] = (short)f2bf(f1.y);
        a[6] = (short)f2bf(f1.z); a[7] = (short)f2bf(f1.w);
        #pragma unroll
        for (int nt = 0; nt < 8; nt++) {
            int n = nt * 16 + l15;
            bf16x8 bfr = *(const bf16x8*)&Wt[n * 136 + k0];
            acc[nt] = __builtin_amdgcn_mfma_f32_16x16x32_bf16(a, bfr, acc[nt], 0, 0, 0);
        }
    }

    float part[4] = {0.f, 0.f, 0.f, 0.f};
    #pragma unroll
    for (int nt = 0; nt < 8; nt++) {
        int n = nt * 16 + l15;
        float bb = b1[n], ww = W2[n];
        #pragma unroll
        for (int i = 0; i < 4; i++) {
            float t = tanh_fast(acc[nt][i] + bb);
            part[i] = fmaf(t, ww, part[i]);
        }
    }
    #pragma unroll
    for (int msk = 1; msk < 16; msk <<= 1)
        #pragma unroll
        for (int i = 0; i < 4; i++) part[i] += __shfl_xor(part[i], msk);
    if (l15 == 0) {
        #pragma unroll
        for (int i = 0; i < 4; i++) {
            long R = row0 + quad * 4 + i;
            if (R < NROWS) atomicAdd(&hsum[(int)(R % 3)], part[i]);
        }
    }
    __syncthreads();
    if (tid < 3) atomicAdd(&w_sum[tid], hsum[tid]);
}

// ---------------------------------------------------------------------------
// combine + inline finalize: every block recomputes the 3-way softmax (cheap)
__global__ void combine_kernel(const float* __restrict__ zm, const float* __restrict__ w_sum,
                               float* __restrict__ out, float* __restrict__ out_att) {
    float w0 = w_sum[0] * (1.f / (float)N_DST);
    float w1 = w_sum[1] * (1.f / (float)N_DST);
    float w2 = w_sum[2] * (1.f / (float)N_DST);
    float m = fmaxf(w0, fmaxf(w1, w2));
    float e0 = __expf(w0 - m), e1 = __expf(w1 - m), e2 = __expf(w2 - m);
    float s = 1.f / (e0 + e1 + e2);
    float a0 = e0 * s, a1 = e1 * s, a2 = e2 * s;
    if (blockIdx.x == 0 && threadIdx.x < 3)
        out_att[threadIdx.x] = threadIdx.x == 0 ? a0 : (threadIdx.x == 1 ? a1 : a2);
    int id4 = blockIdx.x * 256 + threadIdx.x;
    int n  = id4 >> 5;
    int d4 = (id4 & 31) * 4;
    const float4 z0 = *(const float4*)&zm[((size_t)n * 3 + 0) * 128 + d4];
    const float4 z1 = *(const float4*)&zm[((size_t)n * 3 + 1) * 128 + d4];
    const float4 z2 = *(const float4*)&zm[((size_t)n * 3 + 2) * 128 + d4];
    float4 o;
    o.x = a0 * z0.x + a1 * z1.x + a2 * z2.x;
    o.y = a0 * z0.y + a1 * z1.y + a2 * z2.y;
    o.z = a0 * z0.z + a1 * z1.z + a2 * z2.z;
    o.w = a0 * z0.w + a1 * z1.w + a2 * z2.w;
    *(float4*)&out[(size_t)n * 128 + d4] = o;
}

// ---------------------------------------------------------------------------
extern "C" void kernel_launch(void* const* d_in, const int* in_sizes, int n_in,
                              void* d_out, int out_size, void* d_ws, size_t ws_size,
                              hipStream_t stream) {
    const float* dstf   = (const float*)d_in[0];
    const float* src0   = (const float*)d_in[1];
    const float* src1   = (const float*)d_in[2];
    const float* src2   = (const float*)d_in[3];
    const float* sem_W1 = (const float*)d_in[4];
    const float* sem_b1 = (const float*)d_in[5];
    const float* sem_W2 = (const float*)d_in[6];
    const float* Wg[3]  = {(const float*)d_in[7],  (const float*)d_in[13], (const float*)d_in[19]};
    const float* al[3]  = {(const float*)d_in[8],  (const float*)d_in[14], (const float*)d_in[20]};
    const float* ar[3]  = {(const float*)d_in[9],  (const float*)d_in[15], (const float*)d_in[21]};
    const float* bg[3]  = {(const float*)d_in[10], (const float*)d_in[16], (const float*)d_in[22]};
    const int*  sidx[3] = {(const int*)d_in[11], (const int*)d_in[17], (const int*)d_in[23]};
    const int*  didx[3] = {(const int*)d_in[12], (const int*)d_in[18], (const int*)d_in[24]};
    float* out = (float*)d_out;

    char* p = (char*)d_ws;
    auto alloc = [&](size_t bytes) -> char* {
        char* q = p; p += (bytes + 255) & ~(size_t)255; return q;
    };
    float*    zm   = (float*)alloc((size_t)N_DST * 3 * 128 * 4);    // 76.8 MB (pairs aliases)
    ushort_t* hs   = (ushort_t*)alloc((size_t)3 * N_SRC * 128 * 2); // 38.4 MB bf16
    float*    elv  = (float*)alloc((size_t)6 * N_DST * 4);
    float*    wv   = (float*)alloc((size_t)3 * 128 * 4);
    float*    wsum = (float*)alloc((size_t)8 * 4);
    ushort_t* Wt_g = (ushort_t*)alloc((size_t)128 * 128 * 2);
    int* cnts       = (int*)alloc((size_t)3 * N_DST * 4);
    int* offs       = (int*)alloc((size_t)3 * N_DST * 4);
    int* perm       = (int*)alloc((size_t)3 * NE * 4);
    int* bucketCnt  = (int*)alloc((size_t)3 * NB * 4);
    int* bucketBase = (int*)alloc((size_t)3 * (NB + 1) * 4);
    int* bucketCur  = (int*)alloc((size_t)3 * NB * 4);
    int2* pairs = (int2*)zm;    // dead before aggregate writes zm

    hipMemsetAsync(bucketCnt, 0, (size_t)3 * NB * 4, stream);
    hipMemsetAsync(wsum, 0, (size_t)8 * 4, stream);

    vec_kernel<<<3, 128, 0, stream>>>(Wg[0], Wg[1], Wg[2], ar[0], ar[1], ar[2], wv);
    er_kernel<<<12500, 256, 0, stream>>>(dstf, wv, elv);
    prep_w1_kernel<<<64, 256, 0, stream>>>(sem_W1, Wt_g);

    bucket_hist_kernel<<<3 * NBLK_REL, 256, 0, stream>>>(didx[0], didx[1], didx[2], bucketCnt);
    bucket_scan_kernel<<<3, 256, 0, stream>>>(bucketCnt, bucketBase, bucketCur);
    bucket_scatter_kernel<<<3 * NBLK_REL, 256, 0, stream>>>(didx[0], didx[1], didx[2],
                                                            sidx[0], sidx[1], sidx[2],
                                                            bucketCur, pairs);
    csr_kernel<<<3 * NB, 256, 0, stream>>>(pairs, bucketBase, offs, cnts, perm);

    gemm_kernel<<<3 * GEMM_BLKS, 256, 0, stream>>>(src0, src1, src2,
                                                   Wg[0], Wg[1], Wg[2],
                                                   al[0], al[1], al[2], hs, elv);
    aggregate_kernel<<<3 * 12500, 256, 0, stream>>>(hs, elv, perm, offs, cnts,
                                                    bg[0], bg[1], bg[2], zm);
    semantic_kernel<<<(3 * N_DST + 63) / 64, 256, 0, stream>>>(zm, Wt_g, sem_b1, sem_W2, wsum);
    combine_kernel<<<6250, 256, 0, stream>>>(zm, wsum, out, out + (size_t)N_DST * 128);
}

// Round 6
// 493.505 us; speedup vs baseline: 2.0102x; 1.0099x over previous
//
#include <hip/hip_runtime.h>
#include <math.h>

#define D_DIM 128
#define N_DST 50000
#define N_SRC 50000
#define NE    800000
#define NEG_SLOPE 0.2f

#define NB        196      // coarse buckets: dst>>8
#define CAP       4608     // fixed bucket capacity (λ=4082, +8.2σ)
#define CHUNK     8192
#define NBLK_REL  98       // ceil(NE / CHUNK)
#define GEMM_BLKS 391      // ceil(N_SRC / 128) — 128 rows/block (4 waves × 32)
#define GEMM_GRID (3 * GEMM_BLKS)

typedef unsigned short ushort_t;
using f32x4  = __attribute__((ext_vector_type(4))) float;
using bf16x8 = __attribute__((ext_vector_type(8))) short;

__device__ __forceinline__ ushort_t f2bf(float x) {
    unsigned u = __float_as_uint(x);
    unsigned r = (u + 0x7fffu + ((u >> 16) & 1u)) >> 16;
    return (ushort_t)r;
}
__device__ __forceinline__ float bf2f(ushort_t b) {
    return __uint_as_float(((unsigned)b) << 16);
}
__device__ __forceinline__ float bflo(unsigned u) { return __uint_as_float(u << 16); }
__device__ __forceinline__ float bfhi(unsigned u) { return __uint_as_float(u & 0xffff0000u); }
__device__ __forceinline__ float tanh_fast(float x) {
    float e = __expf(2.f * x);
    return 1.f - 2.f / (e + 1.f);
}

// ---------------------------------------------------------------------------
// merged prep: [0,3) wv_r = Wg_r @ ar_r ; [3,67) W1^T -> bf16 Wt_g ;
// [67,259) Wg^T -> bf16 hi/lo fragments (split-bf16 GEMM operands)
__global__ __launch_bounds__(256) void vecprep_kernel(
        const float* __restrict__ Wg0, const float* __restrict__ Wg1,
        const float* __restrict__ Wg2,
        const float* __restrict__ ar0, const float* __restrict__ ar1,
        const float* __restrict__ ar2,
        const float* __restrict__ W1,
        float* __restrict__ wv, ushort_t* __restrict__ Wt_g,
        ushort_t* __restrict__ WgT_hi, ushort_t* __restrict__ WgT_lo) {
    int bx = blockIdx.x, tid = threadIdx.x;
    if (bx < 3) {
        if (tid < 128) {
            const float* W  = bx == 0 ? Wg0 : (bx == 1 ? Wg1 : Wg2);
            const float* ar = bx == 0 ? ar0 : (bx == 1 ? ar1 : ar2);
            float sar = 0.f;
            for (int j = 0; j < D_DIM; j++) sar = fmaf(W[tid * D_DIM + j], ar[j], sar);
            wv[bx * D_DIM + tid] = sar;
        }
    } else if (bx < 67) {
        int idx = (bx - 3) * 256 + tid;           // 16384
        int k = idx >> 7, n = idx & 127;
        Wt_g[n * 128 + k] = f2bf(W1[idx]);
    } else {
        int q = bx - 67;
        int rel = q >> 6;
        int idx = (q & 63) * 256 + tid;           // 16384 per rel
        const float* W = rel == 0 ? Wg0 : (rel == 1 ? Wg1 : Wg2);
        int k = idx >> 7, n = idx & 127;
        float v = W[idx];
        ushort_t hi = f2bf(v);
        float lo = v - bf2f(hi);
        WgT_hi[rel * 16384 + n * 128 + k] = hi;
        WgT_lo[rel * 16384 + n * 128 + k] = f2bf(lo);
    }
}

// ---------------------------------------------------------------------------
// bucket scatter, fixed-capacity regions (no hist/scan passes).
// Per-block LDS counts -> one global atomic per (block,bucket) -> LDS ranks.
__global__ __launch_bounds__(256) void bucket_scatter_kernel(
        const int* __restrict__ d0, const int* __restrict__ d1, const int* __restrict__ d2,
        const int* __restrict__ s0, const int* __restrict__ s1, const int* __restrict__ s2,
        int* __restrict__ bucketCur, int2* __restrict__ pairs) {
    __shared__ int cnt[NB], base[NB], cur[NB];
    int bx = blockIdx.x;
    int r = bx / NBLK_REL, blk = bx % NBLK_REL;
    const int* dd = r == 0 ? d0 : (r == 1 ? d1 : d2);
    const int* ss = r == 0 ? s0 : (r == 1 ? s1 : s2);
    int tid = threadIdx.x;
    if (tid < NB) { cnt[tid] = 0; cur[tid] = 0; }
    __syncthreads();
    int e0 = blk * CHUNK, e1 = min(e0 + CHUNK, NE);
    for (int e = e0 + tid; e < e1; e += 256) atomicAdd(&cnt[dd[e] >> 8], 1);
    __syncthreads();
    if (tid < NB) base[tid] = cnt[tid] ? atomicAdd(&bucketCur[r * NB + tid], cnt[tid]) : 0;
    __syncthreads();
    for (int e = e0 + tid; e < e1; e += 256) {
        int d = dd[e], b = d >> 8;
        int rank = atomicAdd(&cur[b], 1);
        pairs[(size_t)(r * NB + b) * CAP + base[b] + rank] = make_int2(ss[e], d);
    }
}

// per-bucket fine CSR into fixed-capacity perm regions
__global__ __launch_bounds__(256) void csr_kernel(
        const int2* __restrict__ pairs, const int* __restrict__ bucketCur,
        int* __restrict__ offs, int* __restrict__ cnts, int* __restrict__ perm) {
    __shared__ int hist[256], sc[256], cur[256];
    int bx = blockIdx.x;
    int r = bx / NB, b = bx % NB;
    int tid = threadIdx.x;
    int nE = bucketCur[r * NB + b];
    size_t region = (size_t)(r * NB + b) * CAP;
    const int2* pr = pairs + region;
    hist[tid] = 0;
    __syncthreads();
    for (int i = tid; i < nE; i += 256) atomicAdd(&hist[pr[i].y & 255], 1);
    __syncthreads();
    int v = hist[tid];
    sc[tid] = v;
    __syncthreads();
    for (int off = 1; off < 256; off <<= 1) {
        int t = tid >= off ? sc[tid - off] : 0;
        __syncthreads();
        sc[tid] += t;
        __syncthreads();
    }
    int excl = sc[tid] - v;
    int dstg = b * 256 + tid;
    if (dstg < N_DST) { offs[r * N_DST + dstg] = (int)region + excl; cnts[r * N_DST + dstg] = v; }
    cur[tid] = excl;
    __syncthreads();
    int* pm = perm + region;
    for (int i = tid; i < nE; i += 256) {
        int2 p = pr[i];
        int rank = atomicAdd(&cur[p.y & 255], 1);
        pm[rank] = p.x;
    }
}

// ---------------------------------------------------------------------------
// split-bf16 MFMA GEMM (+ fused el epilogue) + er matvec as extra blocks.
// hs = bf16(src @ Wg) computed as hi*hi + hi*lo + lo*hi (fp32-grade).
// Wave = 32 rows (2 x 16-row MFMA tiles), block = 4 waves = 128 rows.
__global__ __launch_bounds__(256) void gemm_er_kernel(
        const float* __restrict__ A0, const float* __restrict__ A1, const float* __restrict__ A2,
        const ushort_t* __restrict__ WgT_hi, const ushort_t* __restrict__ WgT_lo,
        const float* __restrict__ al0, const float* __restrict__ al1, const float* __restrict__ al2,
        const float* __restrict__ dstf, const float* __restrict__ wv,
        ushort_t* __restrict__ hs, float* __restrict__ elv) {
    int bx = blockIdx.x;
    if (bx >= GEMM_GRID) {
        // ---- er path: er_r[n] = dot(dstf[n,:], wv_r) ----
        int eb   = bx - GEMM_GRID;
        int wave = threadIdx.x >> 6, lane = threadIdx.x & 63;
        int row  = eb * 4 + wave;
        const float* mr = dstf + (size_t)row * D_DIM;
        float m0 = mr[lane], m1 = mr[lane + 64];
        #pragma unroll
        for (int r = 0; r < 3; r++) {
            float p = fmaf(m0, wv[r * 128 + lane], m1 * wv[r * 128 + lane + 64]);
            #pragma unroll
            for (int off = 32; off > 0; off >>= 1) p += __shfl_down(p, off);
            if (lane == 0) elv[(3 + r) * N_DST + row] = p;
        }
        return;
    }
    // ---- gemm path ----
    __shared__ float ltr[4][16][132];
    int rel = bx / GEMM_BLKS, blk = bx % GEMM_BLKS;
    const float* A  = rel == 0 ? A0 : (rel == 1 ? A1 : A2);
    const float* al = rel == 0 ? al0 : (rel == 1 ? al1 : al2);
    const ushort_t* Bh = WgT_hi + rel * 16384;
    const ushort_t* Bl = WgT_lo + rel * 16384;
    ushort_t* C = hs + (size_t)rel * N_SRC * 128;

    int w = threadIdx.x >> 6, lane = threadIdx.x & 63;
    int quad = lane >> 4, l15 = lane & 15;
    int row0 = blk * 128 + w * 32;                 // wave's 32 rows

    f32x4 acc[2][8] = {};
    #pragma unroll
    for (int kc = 0; kc < 4; kc++) {
        int k0 = kc * 32 + quad * 8;
        // A fragments (hi/lo) for both 16-row tiles
        bf16x8 ah[2], alo[2];
        #pragma unroll
        for (int t = 0; t < 2; t++) {
            int rA = row0 + t * 16 + l15;
            if (rA > N_SRC - 1) rA = N_SRC - 1;
            const float* src = A + (size_t)rA * 128 + k0;
            float4 f0 = *(const float4*)src;
            float4 f1 = *(const float4*)(src + 4);
            float fv[8] = {f0.x, f0.y, f0.z, f0.w, f1.x, f1.y, f1.z, f1.w};
            #pragma unroll
            for (int j = 0; j < 8; j++) {
                ushort_t h = f2bf(fv[j]);
                ah[t][j]  = (short)h;
                alo[t][j] = (short)f2bf(fv[j] - bf2f(h));
            }
        }
        // B hi fragments: hi*hi and lo*hi
        #pragma unroll
        for (int nt = 0; nt < 8; nt++) {
            bf16x8 bh = *(const bf16x8*)&Bh[(nt * 16 + l15) * 128 + k0];
            #pragma unroll
            for (int t = 0; t < 2; t++) {
                acc[t][nt] = __builtin_amdgcn_mfma_f32_16x16x32_bf16(ah[t],  bh, acc[t][nt], 0, 0, 0);
                acc[t][nt] = __builtin_amdgcn_mfma_f32_16x16x32_bf16(alo[t], bh, acc[t][nt], 0, 0, 0);
            }
        }
        // B lo fragments: hi*lo
        #pragma unroll
        for (int nt = 0; nt < 8; nt++) {
            bf16x8 bl = *(const bf16x8*)&Bl[(nt * 16 + l15) * 128 + k0];
            #pragma unroll
            for (int t = 0; t < 2; t++)
                acc[t][nt] = __builtin_amdgcn_mfma_f32_16x16x32_bf16(ah[t], bl, acc[t][nt], 0, 0, 0);
        }
    }

    // al values for this lane's 8 columns
    float alv[8];
    #pragma unroll
    for (int nt = 0; nt < 8; nt++) alv[nt] = al[nt * 16 + l15];

    #pragma unroll
    for (int t = 0; t < 2; t++) {
        // el epilogue: row sums of acc * al, reduced over the 16 col-lanes
        float part[4] = {0.f, 0.f, 0.f, 0.f};
        #pragma unroll
        for (int nt = 0; nt < 8; nt++)
            #pragma unroll
            for (int i = 0; i < 4; i++)
                part[i] = fmaf(acc[t][nt][i], alv[nt], part[i]);
        #pragma unroll
        for (int msk = 1; msk < 16; msk <<= 1)
            #pragma unroll
            for (int i = 0; i < 4; i++) part[i] += __shfl_xor(part[i], msk);
        if (l15 == 0) {
            #pragma unroll
            for (int i = 0; i < 4; i++) {
                int gr = row0 + t * 16 + quad * 4 + i;
                if (gr < N_SRC) elv[rel * N_DST + gr] = part[i];
            }
        }
        // hs store via per-wave LDS transpose (C-layout -> row-major bf16)
        #pragma unroll
        for (int nt = 0; nt < 8; nt++)
            #pragma unroll
            for (int i = 0; i < 4; i++)
                ltr[w][quad * 4 + i][nt * 16 + l15] = acc[t][nt][i];
        __asm__ __volatile__("" ::: "memory");   // wave-lockstep; compiler orders LDS ops
        int lr = lane & 15;                      // tile-local row
        int c0 = quad * 32;                      // 32-col chunk
        int gr = row0 + t * 16 + lr;
        if (gr < N_SRC) {
            ushort_t* dst = C + (size_t)gr * 128 + c0;
            #pragma unroll
            for (int cc = 0; cc < 4; cc++) {
                float4 f = *(const float4*)&ltr[w][lr][c0 + cc * 8];
                float4 g = *(const float4*)&ltr[w][lr][c0 + cc * 8 + 4];
                ushort4 u0 = make_ushort4(f2bf(f.x), f2bf(f.y), f2bf(f.z), f2bf(f.w));
                ushort4 u1 = make_ushort4(f2bf(g.x), f2bf(g.y), f2bf(g.z), f2bf(g.w));
                *(ushort4*)(dst + cc * 8)     = u0;
                *(ushort4*)(dst + cc * 8 + 4) = u1;
            }
        }
        __asm__ __volatile__("" ::: "memory");
    }
}

// ---------------------------------------------------------------------------
// edge softmax + aggregation: one WAVE per dst, 4 waves/block (unchanged r5)
__global__ __launch_bounds__(256) void aggregate_kernel(
        const ushort_t* __restrict__ hs, const float* __restrict__ elv,
        const int* __restrict__ perm, const int* __restrict__ offs,
        const int* __restrict__ cnts,
        const float* __restrict__ bg0, const float* __restrict__ bg1,
        const float* __restrict__ bg2, float* __restrict__ zm) {
    __shared__ int2 ew[4][128];
    int wave = threadIdx.x >> 6, lane = threadIdx.x & 63;
    int bx  = blockIdx.x;
    int rel = bx / 12500;
    int b   = (bx % 12500) * 4 + wave;
    const float* el  = elv + rel * N_DST;
    float erb = elv[(3 + rel) * N_DST + b];
    const float* bg = rel == 0 ? bg0 : (rel == 1 ? bg1 : bg2);
    const ushort_t* hsr = hs + (size_t)rel * N_SRC * 128;
    int o0 = offs[rel * N_DST + b], deg = cnts[rel * N_DST + b];
    float* zout = zm + ((size_t)b * 3 + rel) * 128;

    if (deg <= 128) {
        int i0 = lane, i1 = lane + 64;
        int s0 = 0, s1 = 0;
        float x0 = -INFINITY, x1 = -INFINITY;
        if (i0 < deg) { s0 = perm[o0 + i0]; float x = el[s0] + erb; x0 = x >= 0.f ? x : NEG_SLOPE * x; }
        if (i1 < deg) { s1 = perm[o0 + i1]; float x = el[s1] + erb; x1 = x >= 0.f ? x : NEG_SLOPE * x; }
        float m = fmaxf(x0, x1);
        #pragma unroll
        for (int msk = 1; msk < 64; msk <<= 1) m = fmaxf(m, __shfl_xor(m, msk));
        float e0 = (i0 < deg) ? __expf(x0 - m) : 0.f;
        float e1 = (i1 < deg) ? __expf(x1 - m) : 0.f;
        float lsum = e0 + e1;
        #pragma unroll
        for (int msk = 1; msk < 64; msk <<= 1) lsum += __shfl_xor(lsum, msk);
        float invz = deg > 0 ? 1.f / lsum : 0.f;

        ew[wave][i0] = make_int2(s0 * 256, __float_as_int(e0 * invz));
        ew[wave][i1] = make_int2(s1 * 256, __float_as_int(e1 * invz));
        __asm__ __volatile__("" ::: "memory");

        int degp = (deg + 7) & ~7;
        const char* base = (const char*)hsr;
        int half = lane >> 5;
        int col8 = (lane & 31) * 8;
        float2 a01 = {0.f, 0.f}, a23 = {0.f, 0.f};
        for (int j = 0; j < degp; j += 8) {
            int2 pA = ew[wave][j + half];
            int2 pB = ew[wave][j + 2 + half];
            int2 pC = ew[wave][j + 4 + half];
            int2 pD = ew[wave][j + 6 + half];
            uint2 hA = *(const uint2*)(base + (unsigned)(pA.x + col8));
            uint2 hB = *(const uint2*)(base + (unsigned)(pB.x + col8));
            uint2 hC = *(const uint2*)(base + (unsigned)(pC.x + col8));
            uint2 hD = *(const uint2*)(base + (unsigned)(pD.x + col8));
            float eA = __int_as_float(pA.y), eB = __int_as_float(pB.y);
            float eC = __int_as_float(pC.y), eD = __int_as_float(pD.y);
            a01.x = fmaf(eA, bflo(hA.x), a01.x); a01.y = fmaf(eA, bfhi(hA.x), a01.y);
            a23.x = fmaf(eA, bflo(hA.y), a23.x); a23.y = fmaf(eA, bfhi(hA.y), a23.y);
            a01.x = fmaf(eB, bflo(hB.x), a01.x); a01.y = fmaf(eB, bfhi(hB.x), a01.y);
            a23.x = fmaf(eB, bflo(hB.y), a23.x); a23.y = fmaf(eB, bfhi(hB.y), a23.y);
            a01.x = fmaf(eC, bflo(hC.x), a01.x); a01.y = fmaf(eC, bfhi(hC.x), a01.y);
            a23.x = fmaf(eC, bflo(hC.y), a23.x); a23.y = fmaf(eC, bfhi(hC.y), a23.y);
            a01.x = fmaf(eD, bflo(hD.x), a01.x); a01.y = fmaf(eD, bfhi(hD.x), a01.y);
            a23.x = fmaf(eD, bflo(hD.y), a23.x); a23.y = fmaf(eD, bfhi(hD.y), a23.y);
        }
        a01.x += __shfl_xor(a01.x, 32);
        a01.y += __shfl_xor(a01.y, 32);
        a23.x += __shfl_xor(a23.x, 32);
        a23.y += __shfl_xor(a23.y, 32);
        if (half == 0) {
            int col4 = (lane & 31) * 4;
            float4 bgv = *(const float4*)&bg[col4];
            float4 z;
            z.x = a01.x + bgv.x;
            z.y = a01.y + bgv.y;
            z.z = a23.x + bgv.z;
            z.w = a23.y + bgv.w;
            z.x = z.x > 0.f ? z.x : expm1f(z.x);
            z.y = z.y > 0.f ? z.y : expm1f(z.y);
            z.z = z.z > 0.f ? z.z : expm1f(z.z);
            z.w = z.w > 0.f ? z.w : expm1f(z.w);
            *(float4*)&zout[col4] = z;
        }
    } else {
        float lmax = -INFINITY;
        for (int i = lane; i < deg; i += 64) {
            int s = perm[o0 + i];
            float x = el[s] + erb;
            x = x >= 0.f ? x : NEG_SLOPE * x;
            lmax = fmaxf(lmax, x);
        }
        #pragma unroll
        for (int msk = 1; msk < 64; msk <<= 1) lmax = fmaxf(lmax, __shfl_xor(lmax, msk));
        float lsum = 0.f;
        for (int i = lane; i < deg; i += 64) {
            int s = perm[o0 + i];
            float x = el[s] + erb;
            x = x >= 0.f ? x : NEG_SLOPE * x;
            lsum += __expf(x - lmax);
        }
        #pragma unroll
        for (int msk = 1; msk < 64; msk <<= 1) lsum += __shfl_xor(lsum, msk);
        float invz = 1.f / lsum;
        float c0 = 0.f, c1 = 0.f;
        int col2 = lane * 2;
        for (int j = 0; j < deg; j++) {
            int s = perm[o0 + j];
            float x = el[s] + erb;
            x = x >= 0.f ? x : NEG_SLOPE * x;
            float e_ = __expf(x - lmax) * invz;
            unsigned hv = *(const unsigned*)(hsr + (size_t)s * 128 + col2);
            c0 = fmaf(e_, bflo(hv), c0);
            c1 = fmaf(e_, bfhi(hv), c1);
        }
        float2 z;
        z.x = c0 + bg[col2];
        z.y = c1 + bg[col2 + 1];
        z.x = z.x > 0.f ? z.x : expm1f(z.x);
        z.y = z.y > 0.f ? z.y : expm1f(z.y);
        *(float2*)&zout[col2] = z;
    }
}

// ---------------------------------------------------------------------------
// semantic attention via bf16 MFMA (unchanged r5)
__global__ __launch_bounds__(256) void semantic_kernel(
        const float* __restrict__ zm, const ushort_t* __restrict__ Wt_g,
        const float* __restrict__ b1, const float* __restrict__ W2,
        float* __restrict__ w_sum) {
    __shared__ ushort_t Wt[128 * 136];
    __shared__ float hsum[3];
    const int NROWS = N_DST * 3;
    int tid = threadIdx.x;
    if (tid < 3) hsum[tid] = 0.f;

    #pragma unroll
    for (int i = 0; i < 8; i++) {
        int c = i * 256 + tid;
        int n = c >> 4, c16 = c & 15;
        uint4 t = *(const uint4*)(Wt_g + n * 128 + c16 * 8);
        *(uint4*)&Wt[n * 136 + c16 * 8] = t;
    }
    __syncthreads();

    int w    = tid >> 6, lane = tid & 63;
    int quad = lane >> 4, l15 = lane & 15;
    long row0 = (long)blockIdx.x * 64 + w * 16;
    long rA = row0 + l15; if (rA > NROWS - 1) rA = NROWS - 1;

    f32x4 acc[8] = {};
    #pragma unroll
    for (int kc = 0; kc < 4; kc++) {
        int k0 = kc * 32 + quad * 8;
        const float* src = zm + (size_t)rA * 128 + k0;
        float4 f0 = *(const float4*)src;
        float4 f1 = *(const float4*)(src + 4);
        bf16x8 a;
        a[0] = (short)f2bf(f0.x); a[1] = (short)f2bf(f0.y);
        a[2] = (short)f2bf(f0.z); a[3] = (short)f2bf(f0.w);
        a[4] = (short)f2bf(f1.x); a[5] = (short)f2bf(f1.y);
        a[6] = (short)f2bf(f1.z); a[7] = (short)f2bf(f1.w);
        #pragma unroll
        for (int nt = 0; nt < 8; nt++) {
            int n = nt * 16 + l15;
            bf16x8 bfr = *(const bf16x8*)&Wt[n * 136 + k0];
            acc[nt] = __builtin_amdgcn_mfma_f32_16x16x32_bf16(a, bfr, acc[nt], 0, 0, 0);
        }
    }

    float part[4] = {0.f, 0.f, 0.f, 0.f};
    #pragma unroll
    for (int nt = 0; nt < 8; nt++) {
        int n = nt * 16 + l15;
        float bb = b1[n], ww = W2[n];
        #pragma unroll
        for (int i = 0; i < 4; i++) {
            float t = tanh_fast(acc[nt][i] + bb);
            part[i] = fmaf(t, ww, part[i]);
        }
    }
    #pragma unroll
    for (int msk = 1; msk < 16; msk <<= 1)
        #pragma unroll
        for (int i = 0; i < 4; i++) part[i] += __shfl_xor(part[i], msk);
    if (l15 == 0) {
        #pragma unroll
        for (int i = 0; i < 4; i++) {
            long R = row0 + quad * 4 + i;
            if (R < NROWS) atomicAdd(&hsum[(int)(R % 3)], part[i]);
        }
    }
    __syncthreads();
    if (tid < 3) atomicAdd(&w_sum[tid], hsum[tid]);
}

// ---------------------------------------------------------------------------
__global__ void combine_kernel(const float* __restrict__ zm, const float* __restrict__ w_sum,
                               float* __restrict__ out, float* __restrict__ out_att) {
    float w0 = w_sum[0] * (1.f / (float)N_DST);
    float w1 = w_sum[1] * (1.f / (float)N_DST);
    float w2 = w_sum[2] * (1.f / (float)N_DST);
    float m = fmaxf(w0, fmaxf(w1, w2));
    float e0 = __expf(w0 - m), e1 = __expf(w1 - m), e2 = __expf(w2 - m);
    float s = 1.f / (e0 + e1 + e2);
    float a0 = e0 * s, a1 = e1 * s, a2 = e2 * s;
    if (blockIdx.x == 0 && threadIdx.x < 3)
        out_att[threadIdx.x] = threadIdx.x == 0 ? a0 : (threadIdx.x == 1 ? a1 : a2);
    int id4 = blockIdx.x * 256 + threadIdx.x;
    int n  = id4 >> 5;
    int d4 = (id4 & 31) * 4;
    const float4 z0 = *(const float4*)&zm[((size_t)n * 3 + 0) * 128 + d4];
    const float4 z1 = *(const float4*)&zm[((size_t)n * 3 + 1) * 128 + d4];
    const float4 z2 = *(const float4*)&zm[((size_t)n * 3 + 2) * 128 + d4];
    float4 o;
    o.x = a0 * z0.x + a1 * z1.x + a2 * z2.x;
    o.y = a0 * z0.y + a1 * z1.y + a2 * z2.y;
    o.z = a0 * z0.z + a1 * z1.z + a2 * z2.z;
    o.w = a0 * z0.w + a1 * z1.w + a2 * z2.w;
    *(float4*)&out[(size_t)n * 128 + d4] = o;
}

// ---------------------------------------------------------------------------
extern "C" void kernel_launch(void* const* d_in, const int* in_sizes, int n_in,
                              void* d_out, int out_size, void* d_ws, size_t ws_size,
                              hipStream_t stream) {
    const float* dstf   = (const float*)d_in[0];
    const float* src0   = (const float*)d_in[1];
    const float* src1   = (const float*)d_in[2];
    const float* src2   = (const float*)d_in[3];
    const float* sem_W1 = (const float*)d_in[4];
    const float* sem_b1 = (const float*)d_in[5];
    const float* sem_W2 = (const float*)d_in[6];
    const float* Wg[3]  = {(const float*)d_in[7],  (const float*)d_in[13], (const float*)d_in[19]};
    const float* al[3]  = {(const float*)d_in[8],  (const float*)d_in[14], (const float*)d_in[20]};
    const float* ar[3]  = {(const float*)d_in[9],  (const float*)d_in[15], (const float*)d_in[21]};
    const float* bg[3]  = {(const float*)d_in[10], (const float*)d_in[16], (const float*)d_in[22]};
    const int*  sidx[3] = {(const int*)d_in[11], (const int*)d_in[17], (const int*)d_in[23]};
    const int*  didx[3] = {(const int*)d_in[12], (const int*)d_in[18], (const int*)d_in[24]};
    float* out = (float*)d_out;

    char* p = (char*)d_ws;
    auto alloc = [&](size_t bytes) -> char* {
        char* q = p; p += (bytes + 255) & ~(size_t)255; return q;
    };
    float*    zm   = (float*)alloc((size_t)N_DST * 3 * 128 * 4);    // 76.8 MB (pairs aliases)
    ushort_t* hs   = (ushort_t*)alloc((size_t)3 * N_SRC * 128 * 2); // 38.4 MB bf16
    float*    elv  = (float*)alloc((size_t)6 * N_DST * 4);
    float*    wv   = (float*)alloc((size_t)3 * 128 * 4);
    ushort_t* Wt_g   = (ushort_t*)alloc((size_t)128 * 128 * 2);
    ushort_t* WgT_hi = (ushort_t*)alloc((size_t)3 * 16384 * 2);
    ushort_t* WgT_lo = (ushort_t*)alloc((size_t)3 * 16384 * 2);
    int* cnts = (int*)alloc((size_t)3 * N_DST * 4);
    int* offs = (int*)alloc((size_t)3 * N_DST * 4);
    int* perm = (int*)alloc((size_t)3 * NB * CAP * 4);              // 10.8 MB
    int* zero = (int*)alloc((size_t)(3 * NB + 8) * 4);              // bucketCur + wsum
    int*   bucketCur = zero;
    float* wsum      = (float*)(zero + 3 * NB);
    int2* pairs = (int2*)zm;    // 21.7 MB alias; dead before aggregate writes zm

    hipMemsetAsync(zero, 0, (size_t)(3 * NB + 8) * 4, stream);

    vecprep_kernel<<<259, 256, 0, stream>>>(Wg[0], Wg[1], Wg[2], ar[0], ar[1], ar[2],
                                            sem_W1, wv, Wt_g, WgT_hi, WgT_lo);
    bucket_scatter_kernel<<<3 * NBLK_REL, 256, 0, stream>>>(didx[0], didx[1], didx[2],
                                                            sidx[0], sidx[1], sidx[2],
                                                            bucketCur, pairs);
    csr_kernel<<<3 * NB, 256, 0, stream>>>(pairs, bucketCur, offs, cnts, perm);
    gemm_er_kernel<<<GEMM_GRID + 12500, 256, 0, stream>>>(src0, src1, src2,
                                                          WgT_hi, WgT_lo,
                                                          al[0], al[1], al[2],
                                                          dstf, wv, hs, elv);
    aggregate_kernel<<<3 * 12500, 256, 0, stream>>>(hs, elv, perm, offs, cnts,
                                                    bg[0], bg[1], bg[2], zm);
    semantic_kernel<<<(3 * N_DST + 63) / 64, 256, 0, stream>>>(zm, Wt_g, sem_b1, sem_W2, wsum);
    combine_kernel<<<6250, 256, 0, stream>>>(zm, wsum, out, out + (size_t)N_DST * 128);
}

// Round 7
// 488.625 us; speedup vs baseline: 2.0302x; 1.0100x over previous
//
#include <hip/hip_runtime.h>
#include <math.h>

#define D_DIM 128
#define N_DST 50000
#define N_SRC 50000
#define NE    800000
#define NEG_SLOPE 0.2f

#define NB        196      // coarse buckets: dst>>8
#define CAP       4608     // fixed bucket capacity (λ=4082, +8.2σ)
#define CHUNK     8192
#define NBLK_REL  98       // ceil(NE / CHUNK)
#define GEMM_BLKS 391      // ceil(N_SRC / 128) — 128 rows/block (4 waves × 32 rows)
#define GEMM_GRID (3 * GEMM_BLKS)

typedef unsigned short ushort_t;
using f32x4  = __attribute__((ext_vector_type(4))) float;
using bf16x8 = __attribute__((ext_vector_type(8))) short;

__device__ __forceinline__ ushort_t f2bf(float x) {
    unsigned u = __float_as_uint(x);
    unsigned r = (u + 0x7fffu + ((u >> 16) & 1u)) >> 16;
    return (ushort_t)r;
}
__device__ __forceinline__ float bf2f(ushort_t b) {
    return __uint_as_float(((unsigned)b) << 16);
}
__device__ __forceinline__ float bflo(unsigned u) { return __uint_as_float(u << 16); }
__device__ __forceinline__ float bfhi(unsigned u) { return __uint_as_float(u & 0xffff0000u); }
__device__ __forceinline__ float tanh_fast(float x) {
    float e = __expf(2.f * x);
    return 1.f - 2.f / (e + 1.f);
}

// ---------------------------------------------------------------------------
// merged prep: [0,3) wv_r = Wg_r @ ar_r ; [3,67) W1^T -> bf16 Wt_g ;
// [67,259) Wg^T -> bf16 hi/lo fragments (split-bf16 GEMM operands)
__global__ __launch_bounds__(256) void vecprep_kernel(
        const float* __restrict__ Wg0, const float* __restrict__ Wg1,
        const float* __restrict__ Wg2,
        const float* __restrict__ ar0, const float* __restrict__ ar1,
        const float* __restrict__ ar2,
        const float* __restrict__ W1,
        float* __restrict__ wv, ushort_t* __restrict__ Wt_g,
        ushort_t* __restrict__ WgT_hi, ushort_t* __restrict__ WgT_lo) {
    int bx = blockIdx.x, tid = threadIdx.x;
    if (bx < 3) {
        if (tid < 128) {
            const float* W  = bx == 0 ? Wg0 : (bx == 1 ? Wg1 : Wg2);
            const float* ar = bx == 0 ? ar0 : (bx == 1 ? ar1 : ar2);
            float sar = 0.f;
            for (int j = 0; j < D_DIM; j++) sar = fmaf(W[tid * D_DIM + j], ar[j], sar);
            wv[bx * D_DIM + tid] = sar;
        }
    } else if (bx < 67) {
        int idx = (bx - 3) * 256 + tid;           // 16384
        int k = idx >> 7, n = idx & 127;
        Wt_g[n * 128 + k] = f2bf(W1[idx]);
    } else {
        int q = bx - 67;
        int rel = q >> 6;
        int idx = (q & 63) * 256 + tid;           // 16384 per rel
        const float* W = rel == 0 ? Wg0 : (rel == 1 ? Wg1 : Wg2);
        int k = idx >> 7, n = idx & 127;
        float v = W[idx];
        ushort_t hi = f2bf(v);
        float lo = v - bf2f(hi);
        WgT_hi[rel * 16384 + n * 128 + k] = hi;
        WgT_lo[rel * 16384 + n * 128 + k] = f2bf(lo);
    }
}

// ---------------------------------------------------------------------------
// bucket scatter, fixed-capacity regions (no hist/scan passes).
__global__ __launch_bounds__(256) void bucket_scatter_kernel(
        const int* __restrict__ d0, const int* __restrict__ d1, const int* __restrict__ d2,
        const int* __restrict__ s0, const int* __restrict__ s1, const int* __restrict__ s2,
        int* __restrict__ bucketCur, int2* __restrict__ pairs) {
    __shared__ int cnt[NB], base[NB], cur[NB];
    int bx = blockIdx.x;
    int r = bx / NBLK_REL, blk = bx % NBLK_REL;
    const int* dd = r == 0 ? d0 : (r == 1 ? d1 : d2);
    const int* ss = r == 0 ? s0 : (r == 1 ? s1 : s2);
    int tid = threadIdx.x;
    if (tid < NB) { cnt[tid] = 0; cur[tid] = 0; }
    __syncthreads();
    int e0 = blk * CHUNK, e1 = min(e0 + CHUNK, NE);
    for (int e = e0 + tid; e < e1; e += 256) atomicAdd(&cnt[dd[e] >> 8], 1);
    __syncthreads();
    if (tid < NB) base[tid] = cnt[tid] ? atomicAdd(&bucketCur[r * NB + tid], cnt[tid]) : 0;
    __syncthreads();
    for (int e = e0 + tid; e < e1; e += 256) {
        int d = dd[e], b = d >> 8;
        int rank = atomicAdd(&cur[b], 1);
        pairs[(size_t)(r * NB + b) * CAP + base[b] + rank] = make_int2(ss[e], d);
    }
}

// per-bucket fine CSR into fixed-capacity perm regions
__global__ __launch_bounds__(256) void csr_kernel(
        const int2* __restrict__ pairs, const int* __restrict__ bucketCur,
        int* __restrict__ offs, int* __restrict__ cnts, int* __restrict__ perm) {
    __shared__ int hist[256], sc[256], cur[256];
    int bx = blockIdx.x;
    int r = bx / NB, b = bx % NB;
    int tid = threadIdx.x;
    int nE = bucketCur[r * NB + b];
    size_t region = (size_t)(r * NB + b) * CAP;
    const int2* pr = pairs + region;
    hist[tid] = 0;
    __syncthreads();
    for (int i = tid; i < nE; i += 256) atomicAdd(&hist[pr[i].y & 255], 1);
    __syncthreads();
    int v = hist[tid];
    sc[tid] = v;
    __syncthreads();
    for (int off = 1; off < 256; off <<= 1) {
        int t = tid >= off ? sc[tid - off] : 0;
        __syncthreads();
        sc[tid] += t;
        __syncthreads();
    }
    int excl = sc[tid] - v;
    int dstg = b * 256 + tid;
    if (dstg < N_DST) { offs[r * N_DST + dstg] = (int)region + excl; cnts[r * N_DST + dstg] = v; }
    cur[tid] = excl;
    __syncthreads();
    int* pm = perm + region;
    for (int i = tid; i < nE; i += 256) {
        int2 p = pr[i];
        int rank = atomicAdd(&cur[p.y & 255], 1);
        pm[rank] = p.x;
    }
}

// ---------------------------------------------------------------------------
// split-bf16 MFMA GEMM with per-wave coalesced LDS staging (+ fused el) +
// er matvec as extra blocks. NO block barriers in the gemm path — all LDS
// traffic is wave-private (lockstep), compiler fences only.
// Wave = 32 rows × 128 cols: acc[2 row-tiles][8 col-tiles].
__global__ __launch_bounds__(256) void gemm_er_kernel(
        const float* __restrict__ A0, const float* __restrict__ A1, const float* __restrict__ A2,
        const ushort_t* __restrict__ WgT_hi, const ushort_t* __restrict__ WgT_lo,
        const float* __restrict__ al0, const float* __restrict__ al1, const float* __restrict__ al2,
        const float* __restrict__ dstf, const float* __restrict__ wv,
        ushort_t* __restrict__ hs, float* __restrict__ elv) {
    int bx = blockIdx.x;
    if (bx >= GEMM_GRID) {
        // ---- er path: er_r[n] = dot(dstf[n,:], wv_r) ----
        int eb   = bx - GEMM_GRID;
        int wave = threadIdx.x >> 6, lane = threadIdx.x & 63;
        int row  = eb * 4 + wave;
        const float* mr = dstf + (size_t)row * D_DIM;
        float m0 = mr[lane], m1 = mr[lane + 64];
        #pragma unroll
        for (int r = 0; r < 3; r++) {
            float p = fmaf(m0, wv[r * 128 + lane], m1 * wv[r * 128 + lane + 64]);
            #pragma unroll
            for (int off = 32; off > 0; off >>= 1) p += __shfl_down(p, off);
            if (lane == 0) elv[(3 + r) * N_DST + row] = p;
        }
        return;
    }
    // ---- gemm path ----
    // per-wave LDS region: 2560 ushorts.
    //   K-loop:   Ah[32][40] (0..1279) | Al[32][40] (1280..2559)
    //   epilogue: Csh[32][72] (0..2303), reused sequentially (wave-private)
    __shared__ ushort_t wls[4][2560];
    int rel = bx / GEMM_BLKS, blk = bx % GEMM_BLKS;
    const float* A  = rel == 0 ? A0 : (rel == 1 ? A1 : A2);
    const float* al = rel == 0 ? al0 : (rel == 1 ? al1 : al2);
    const ushort_t* Bh = WgT_hi + rel * 16384;
    const ushort_t* Bl = WgT_lo + rel * 16384;
    ushort_t* C = hs + (size_t)rel * N_SRC * 128;

    int w = threadIdx.x >> 6, lane = threadIdx.x & 63;
    int quad = lane >> 4, l15 = lane & 15;
    int row0 = blk * 128 + w * 32;                 // wave's 32 rows
    ushort_t* Ah = wls[w];
    ushort_t* Al = wls[w] + 1280;

    f32x4 acc[2][8] = {};
    #pragma unroll
    for (int kc = 0; kc < 4; kc++) {
        // stage 32 rows × 32 cols, coalesced (8 rows per wave-load), convert once
        #pragma unroll
        for (int j = 0; j < 4; j++) {
            int pp = lane + j * 64;
            int r = pp >> 3, c4 = (pp & 7) * 4;
            int gr = row0 + r; if (gr > N_SRC - 1) gr = N_SRC - 1;
            float4 f = *(const float4*)&A[(size_t)gr * 128 + kc * 32 + c4];
            ushort4 h4, l4;
            h4.x = f2bf(f.x); l4.x = (ushort_t)(__float_as_uint(f.x - bf2f(h4.x)) >> 16);
            h4.y = f2bf(f.y); l4.y = (ushort_t)(__float_as_uint(f.y - bf2f(h4.y)) >> 16);
            h4.z = f2bf(f.z); l4.z = (ushort_t)(__float_as_uint(f.z - bf2f(h4.z)) >> 16);
            h4.w = f2bf(f.w); l4.w = (ushort_t)(__float_as_uint(f.w - bf2f(h4.w)) >> 16);
            *(ushort4*)&Ah[r * 40 + c4] = h4;
            *(ushort4*)&Al[r * 40 + c4] = l4;
        }
        __asm__ __volatile__("" ::: "memory");
        bf16x8 ah[2], alo[2];
        #pragma unroll
        for (int t = 0; t < 2; t++) {
            ah[t]  = *(const bf16x8*)&Ah[(l15 + t * 16) * 40 + quad * 8];
            alo[t] = *(const bf16x8*)&Al[(l15 + t * 16) * 40 + quad * 8];
        }
        int koff = kc * 32 + quad * 8;
        #pragma unroll
        for (int nt = 0; nt < 8; nt++) {
            bf16x8 bh = *(const bf16x8*)&Bh[(nt * 16 + l15) * 128 + koff];
            bf16x8 bl = *(const bf16x8*)&Bl[(nt * 16 + l15) * 128 + koff];
            #pragma unroll
            for (int t = 0; t < 2; t++) {
                acc[t][nt] = __builtin_amdgcn_mfma_f32_16x16x32_bf16(ah[t],  bh, acc[t][nt], 0, 0, 0);
                acc[t][nt] = __builtin_amdgcn_mfma_f32_16x16x32_bf16(alo[t], bh, acc[t][nt], 0, 0, 0);
                acc[t][nt] = __builtin_amdgcn_mfma_f32_16x16x32_bf16(ah[t],  bl, acc[t][nt], 0, 0, 0);
            }
        }
        __asm__ __volatile__("" ::: "memory");
    }

    // el epilogue: row sums of acc * al, reduced over the 16 col-lanes
    float alv[8];
    #pragma unroll
    for (int nt = 0; nt < 8; nt++) alv[nt] = al[nt * 16 + l15];
    #pragma unroll
    for (int t = 0; t < 2; t++) {
        float part[4] = {0.f, 0.f, 0.f, 0.f};
        #pragma unroll
        for (int nt = 0; nt < 8; nt++)
            #pragma unroll
            for (int i = 0; i < 4; i++)
                part[i] = fmaf(acc[t][nt][i], alv[nt], part[i]);
        #pragma unroll
        for (int msk = 1; msk < 16; msk <<= 1)
            #pragma unroll
            for (int i = 0; i < 4; i++) part[i] += __shfl_xor(part[i], msk);
        if (l15 == 0) {
            #pragma unroll
            for (int i = 0; i < 4; i++) {
                int gr = row0 + t * 16 + quad * 4 + i;
                if (gr < N_SRC) elv[rel * N_DST + gr] = part[i];
            }
        }
    }

    // C epilogue: bf16 transpose through wave-private LDS, two 64-col halves
    ushort_t* Csh = wls[w];                        // [32][72]
    #pragma unroll
    for (int h = 0; h < 2; h++) {
        __asm__ __volatile__("" ::: "memory");
        #pragma unroll
        for (int t = 0; t < 2; t++)
            #pragma unroll
            for (int ntl = 0; ntl < 4; ntl++) {
                int nt = h * 4 + ntl;
                #pragma unroll
                for (int i = 0; i < 4; i++)
                    Csh[(t * 16 + quad * 4 + i) * 72 + ntl * 16 + l15] = f2bf(acc[t][nt][i]);
            }
        __asm__ __volatile__("" ::: "memory");
        int r2 = lane >> 1, cb = (lane & 1) * 32;
        int gr = row0 + r2;
        if (gr < N_SRC) {
            ushort_t* dst = C + (size_t)gr * 128 + h * 64 + cb;
            #pragma unroll
            for (int k2 = 0; k2 < 4; k2++) {
                uint4 v = *(const uint4*)&Csh[r2 * 72 + cb + k2 * 8];
                *(uint4*)(dst + k2 * 8) = v;
            }
        }
    }
}

// ---------------------------------------------------------------------------
// edge softmax + aggregation: one WAVE per dst, 4 waves/block (unchanged)
__global__ __launch_bounds__(256) void aggregate_kernel(
        const ushort_t* __restrict__ hs, const float* __restrict__ elv,
        const int* __restrict__ perm, const int* __restrict__ offs,
        const int* __restrict__ cnts,
        const float* __restrict__ bg0, const float* __restrict__ bg1,
        const float* __restrict__ bg2, float* __restrict__ zm) {
    __shared__ int2 ew[4][128];
    int wave = threadIdx.x >> 6, lane = threadIdx.x & 63;
    int bx  = blockIdx.x;
    int rel = bx / 12500;
    int b   = (bx % 12500) * 4 + wave;
    const float* el  = elv + rel * N_DST;
    float erb = elv[(3 + rel) * N_DST + b];
    const float* bg = rel == 0 ? bg0 : (rel == 1 ? bg1 : bg2);
    const ushort_t* hsr = hs + (size_t)rel * N_SRC * 128;
    int o0 = offs[rel * N_DST + b], deg = cnts[rel * N_DST + b];
    float* zout = zm + ((size_t)b * 3 + rel) * 128;

    if (deg <= 128) {
        int i0 = lane, i1 = lane + 64;
        int s0 = 0, s1 = 0;
        float x0 = -INFINITY, x1 = -INFINITY;
        if (i0 < deg) { s0 = perm[o0 + i0]; float x = el[s0] + erb; x0 = x >= 0.f ? x : NEG_SLOPE * x; }
        if (i1 < deg) { s1 = perm[o0 + i1]; float x = el[s1] + erb; x1 = x >= 0.f ? x : NEG_SLOPE * x; }
        float m = fmaxf(x0, x1);
        #pragma unroll
        for (int msk = 1; msk < 64; msk <<= 1) m = fmaxf(m, __shfl_xor(m, msk));
        float e0 = (i0 < deg) ? __expf(x0 - m) : 0.f;
        float e1 = (i1 < deg) ? __expf(x1 - m) : 0.f;
        float lsum = e0 + e1;
        #pragma unroll
        for (int msk = 1; msk < 64; msk <<= 1) lsum += __shfl_xor(lsum, msk);
        float invz = deg > 0 ? 1.f / lsum : 0.f;

        ew[wave][i0] = make_int2(s0 * 256, __float_as_int(e0 * invz));
        ew[wave][i1] = make_int2(s1 * 256, __float_as_int(e1 * invz));
        __asm__ __volatile__("" ::: "memory");

        int degp = (deg + 7) & ~7;
        const char* base = (const char*)hsr;
        int half = lane >> 5;
        int col8 = (lane & 31) * 8;
        float2 a01 = {0.f, 0.f}, a23 = {0.f, 0.f};
        for (int j = 0; j < degp; j += 8) {
            int2 pA = ew[wave][j + half];
            int2 pB = ew[wave][j + 2 + half];
            int2 pC = ew[wave][j + 4 + half];
            int2 pD = ew[wave][j + 6 + half];
            uint2 hA = *(const uint2*)(base + (unsigned)(pA.x + col8));
            uint2 hB = *(const uint2*)(base + (unsigned)(pB.x + col8));
            uint2 hC = *(const uint2*)(base + (unsigned)(pC.x + col8));
            uint2 hD = *(const uint2*)(base + (unsigned)(pD.x + col8));
            float eA = __int_as_float(pA.y), eB = __int_as_float(pB.y);
            float eC = __int_as_float(pC.y), eD = __int_as_float(pD.y);
            a01.x = fmaf(eA, bflo(hA.x), a01.x); a01.y = fmaf(eA, bfhi(hA.x), a01.y);
            a23.x = fmaf(eA, bflo(hA.y), a23.x); a23.y = fmaf(eA, bfhi(hA.y), a23.y);
            a01.x = fmaf(eB, bflo(hB.x), a01.x); a01.y = fmaf(eB, bfhi(hB.x), a01.y);
            a23.x = fmaf(eB, bflo(hB.y), a23.x); a23.y = fmaf(eB, bfhi(hB.y), a23.y);
            a01.x = fmaf(eC, bflo(hC.x), a01.x); a01.y = fmaf(eC, bfhi(hC.x), a01.y);
            a23.x = fmaf(eC, bflo(hC.y), a23.x); a23.y = fmaf(eC, bfhi(hC.y), a23.y);
            a01.x = fmaf(eD, bflo(hD.x), a01.x); a01.y = fmaf(eD, bfhi(hD.x), a01.y);
            a23.x = fmaf(eD, bflo(hD.y), a23.x); a23.y = fmaf(eD, bfhi(hD.y), a23.y);
        }
        a01.x += __shfl_xor(a01.x, 32);
        a01.y += __shfl_xor(a01.y, 32);
        a23.x += __shfl_xor(a23.x, 32);
        a23.y += __shfl_xor(a23.y, 32);
        if (half == 0) {
            int col4 = (lane & 31) * 4;
            float4 bgv = *(const float4*)&bg[col4];
            float4 z;
            z.x = a01.x + bgv.x;
            z.y = a01.y + bgv.y;
            z.z = a23.x + bgv.z;
            z.w = a23.y + bgv.w;
            z.x = z.x > 0.f ? z.x : expm1f(z.x);
            z.y = z.y > 0.f ? z.y : expm1f(z.y);
            z.z = z.z > 0.f ? z.z : expm1f(z.z);
            z.w = z.w > 0.f ? z.w : expm1f(z.w);
            *(float4*)&zout[col4] = z;
        }
    } else {
        float lmax = -INFINITY;
        for (int i = lane; i < deg; i += 64) {
            int s = perm[o0 + i];
            float x = el[s] + erb;
            x = x >= 0.f ? x : NEG_SLOPE * x;
            lmax = fmaxf(lmax, x);
        }
        #pragma unroll
        for (int msk = 1; msk < 64; msk <<= 1) lmax = fmaxf(lmax, __shfl_xor(lmax, msk));
        float lsum = 0.f;
        for (int i = lane; i < deg; i += 64) {
            int s = perm[o0 + i];
            float x = el[s] + erb;
            x = x >= 0.f ? x : NEG_SLOPE * x;
            lsum += __expf(x - lmax);
        }
        #pragma unroll
        for (int msk = 1; msk < 64; msk <<= 1) lsum += __shfl_xor(lsum, msk);
        float invz = 1.f / lsum;
        float c0 = 0.f, c1 = 0.f;
        int col2 = lane * 2;
        for (int j = 0; j < deg; j++) {
            int s = perm[o0 + j];
            float x = el[s] + erb;
            x = x >= 0.f ? x : NEG_SLOPE * x;
            float e_ = __expf(x - lmax) * invz;
            unsigned hv = *(const unsigned*)(hsr + (size_t)s * 128 + col2);
            c0 = fmaf(e_, bflo(hv), c0);
            c1 = fmaf(e_, bfhi(hv), c1);
        }
        float2 z;
        z.x = c0 + bg[col2];
        z.y = c1 + bg[col2 + 1];
        z.x = z.x > 0.f ? z.x : expm1f(z.x);
        z.y = z.y > 0.f ? z.y : expm1f(z.y);
        *(float2*)&zout[col2] = z;
    }
}

// ---------------------------------------------------------------------------
// semantic attention via bf16 MFMA (unchanged)
__global__ __launch_bounds__(256) void semantic_kernel(
        const float* __restrict__ zm, const ushort_t* __restrict__ Wt_g,
        const float* __restrict__ b1, const float* __restrict__ W2,
        float* __restrict__ w_sum) {
    __shared__ ushort_t Wt[128 * 136];
    __shared__ float hsum[3];
    const int NROWS = N_DST * 3;
    int tid = threadIdx.x;
    if (tid < 3) hsum[tid] = 0.f;

    #pragma unroll
    for (int i = 0; i < 8; i++) {
        int c = i * 256 + tid;
        int n = c >> 4, c16 = c & 15;
        uint4 t = *(const uint4*)(Wt_g + n * 128 + c16 * 8);
        *(uint4*)&Wt[n * 136 + c16 * 8] = t;
    }
    __syncthreads();

    int w    = tid >> 6, lane = tid & 63;
    int quad = lane >> 4, l15 = lane & 15;
    long row0 = (long)blockIdx.x * 64 + w * 16;
    long rA = row0 + l15; if (rA > NROWS - 1) rA = NROWS - 1;

    f32x4 acc[8] = {};
    #pragma unroll
    for (int kc = 0; kc < 4; kc++) {
        int k0 = kc * 32 + quad * 8;
        const float* src = zm + (size_t)rA * 128 + k0;
        float4 f0 = *(const float4*)src;
        float4 f1 = *(const float4*)(src + 4);
        bf16x8 a;
        a[0] = (short)f2bf(f0.x); a[1] = (short)f2bf(f0.y);
        a[2] = (short)f2bf(f0.z); a[3] = (short)f2bf(f0.w);
        a[4] = (short)f2bf(f1.x); a[5] = (short)f2bf(f1.y);
        a[6] = (short)f2bf(f1.z); a[7] = (short)f2bf(f1.w);
        #pragma unroll
        for (int nt = 0; nt < 8; nt++) {
            int n = nt * 16 + l15;
            bf16x8 bfr = *(const bf16x8*)&Wt[n * 136 + k0];
            acc[nt] = __builtin_amdgcn_mfma_f32_16x16x32_bf16(a, bfr, acc[nt], 0, 0, 0);
        }
    }

    float part[4] = {0.f, 0.f, 0.f, 0.f};
    #pragma unroll
    for (int nt = 0; nt < 8; nt++) {
        int n = nt * 16 + l15;
        float bb = b1[n], ww = W2[n];
        #pragma unroll
        for (int i = 0; i < 4; i++) {
            float t = tanh_fast(acc[nt][i] + bb);
            part[i] = fmaf(t, ww, part[i]);
        }
    }
    #pragma unroll
    for (int msk = 1; msk < 16; msk <<= 1)
        #pragma unroll
        for (int i = 0; i < 4; i++) part[i] += __shfl_xor(part[i], msk);
    if (l15 == 0) {
        #pragma unroll
        for (int i = 0; i < 4; i++) {
            long R = row0 + quad * 4 + i;
            if (R < NROWS) atomicAdd(&hsum[(int)(R % 3)], part[i]);
        }
    }
    __syncthreads();
    if (tid < 3) atomicAdd(&w_sum[tid], hsum[tid]);
}

// ---------------------------------------------------------------------------
__global__ void combine_kernel(const float* __restrict__ zm, const float* __restrict__ w_sum,
                               float* __restrict__ out, float* __restrict__ out_att) {
    float w0 = w_sum[0] * (1.f / (float)N_DST);
    float w1 = w_sum[1] * (1.f / (float)N_DST);
    float w2 = w_sum[2] * (1.f / (float)N_DST);
    float m = fmaxf(w0, fmaxf(w1, w2));
    float e0 = __expf(w0 - m), e1 = __expf(w1 - m), e2 = __expf(w2 - m);
    float s = 1.f / (e0 + e1 + e2);
    float a0 = e0 * s, a1 = e1 * s, a2 = e2 * s;
    if (blockIdx.x == 0 && threadIdx.x < 3)
        out_att[threadIdx.x] = threadIdx.x == 0 ? a0 : (threadIdx.x == 1 ? a1 : a2);
    int id4 = blockIdx.x * 256 + threadIdx.x;
    int n  = id4 >> 5;
    int d4 = (id4 & 31) * 4;
    const float4 z0 = *(const float4*)&zm[((size_t)n * 3 + 0) * 128 + d4];
    const float4 z1 = *(const float4*)&zm[((size_t)n * 3 + 1) * 128 + d4];
    const float4 z2 = *(const float4*)&zm[((size_t)n * 3 + 2) * 128 + d4];
    float4 o;
    o.x = a0 * z0.x + a1 * z1.x + a2 * z2.x;
    o.y = a0 * z0.y + a1 * z1.y + a2 * z2.y;
    o.z = a0 * z0.z + a1 * z1.z + a2 * z2.z;
    o.w = a0 * z0.w + a1 * z1.w + a2 * z2.w;
    *(float4*)&out[(size_t)n * 128 + d4] = o;
}

// ---------------------------------------------------------------------------
extern "C" void kernel_launch(void* const* d_in, const int* in_sizes, int n_in,
                              void* d_out, int out_size, void* d_ws, size_t ws_size,
                              hipStream_t stream) {
    const float* dstf   = (const float*)d_in[0];
    const float* src0   = (const float*)d_in[1];
    const float* src1   = (const float*)d_in[2];
    const float* src2   = (const float*)d_in[3];
    const float* sem_W1 = (const float*)d_in[4];
    const float* sem_b1 = (const float*)d_in[5];
    const float* sem_W2 = (const float*)d_in[6];
    const float* Wg[3]  = {(const float*)d_in[7],  (const float*)d_in[13], (const float*)d_in[19]};
    const float* al[3]  = {(const float*)d_in[8],  (const float*)d_in[14], (const float*)d_in[20]};
    const float* ar[3]  = {(const float*)d_in[9],  (const float*)d_in[15], (const float*)d_in[21]};
    const float* bg[3]  = {(const float*)d_in[10], (const float*)d_in[16], (const float*)d_in[22]};
    const int*  sidx[3] = {(const int*)d_in[11], (const int*)d_in[17], (const int*)d_in[23]};
    const int*  didx[3] = {(const int*)d_in[12], (const int*)d_in[18], (const int*)d_in[24]};
    float* out = (float*)d_out;

    char* p = (char*)d_ws;
    auto alloc = [&](size_t bytes) -> char* {
        char* q = p; p += (bytes + 255) & ~(size_t)255; return q;
    };
    float*    zm   = (float*)alloc((size_t)N_DST * 3 * 128 * 4);    // 76.8 MB (pairs aliases)
    ushort_t* hs   = (ushort_t*)alloc((size_t)3 * N_SRC * 128 * 2); // 38.4 MB bf16
    float*    elv  = (float*)alloc((size_t)6 * N_DST * 4);
    float*    wv   = (float*)alloc((size_t)3 * 128 * 4);
    ushort_t* Wt_g   = (ushort_t*)alloc((size_t)128 * 128 * 2);
    ushort_t* WgT_hi = (ushort_t*)alloc((size_t)3 * 16384 * 2);
    ushort_t* WgT_lo = (ushort_t*)alloc((size_t)3 * 16384 * 2);
    int* cnts = (int*)alloc((size_t)3 * N_DST * 4);
    int* offs = (int*)alloc((size_t)3 * N_DST * 4);
    int* perm = (int*)alloc((size_t)3 * NB * CAP * 4);              // 10.8 MB
    int* zero = (int*)alloc((size_t)(3 * NB + 8) * 4);              // bucketCur + wsum
    int*   bucketCur = zero;
    float* wsum      = (float*)(zero + 3 * NB);
    int2* pairs = (int2*)zm;    // 21.7 MB alias; dead before aggregate writes zm

    hipMemsetAsync(zero, 0, (size_t)(3 * NB + 8) * 4, stream);

    vecprep_kernel<<<259, 256, 0, stream>>>(Wg[0], Wg[1], Wg[2], ar[0], ar[1], ar[2],
                                            sem_W1, wv, Wt_g, WgT_hi, WgT_lo);
    bucket_scatter_kernel<<<3 * NBLK_REL, 256, 0, stream>>>(didx[0], didx[1], didx[2],
                                                            sidx[0], sidx[1], sidx[2],
                                                            bucketCur, pairs);
    csr_kernel<<<3 * NB, 256, 0, stream>>>(pairs, bucketCur, offs, cnts, perm);
    gemm_er_kernel<<<GEMM_GRID + 12500, 256, 0, stream>>>(src0, src1, src2,
                                                          WgT_hi, WgT_lo,
                                                          al[0], al[1], al[2],
                                                          dstf, wv, hs, elv);
    aggregate_kernel<<<3 * 12500, 256, 0, stream>>>(hs, elv, perm, offs, cnts,
                                                    bg[0], bg[1], bg[2], zm);
    semantic_kernel<<<(3 * N_DST + 63) / 64, 256, 0, stream>>>(zm, Wt_g, sem_b1, sem_W2, wsum);
    combine_kernel<<<6250, 256, 0, stream>>>(zm, wsum, out, out + (size_t)N_DST * 128);
}